// Round 1
// baseline (6259.078 us; speedup 1.0000x reference)
//
#include <hip/hip_runtime.h>
#include <math.h>

#define NN 20000
#define NE 640000
#define NIN 256
#define NH 8
#define HD 16
#define NM 3
#define NF 128   // H*D

// ---- monotone float<->uint encoding for atomicMax on floats ----
__device__ __forceinline__ unsigned enc_f(float x) {
  unsigned u = __float_as_uint(x);
  return (u & 0x80000000u) ? ~u : (u | 0x80000000u);
}
__device__ __forceinline__ float dec_f(unsigned k) {
  unsigned u = (k & 0x80000000u) ? (k & 0x7FFFFFFFu) : ~k;
  return __uint_as_float(u);
}

__device__ __forceinline__ void atomAddF(float* p, float v) {
  unsafeAtomicAdd(p, v);   // native global_atomic_add_f32 on gfx950
}

// ---- init kernels (ws is poisoned 0xAA; must init everything we read) ----
__global__ void k_init_aggr(const float* __restrict__ bias, float* __restrict__ aggr) {
  int idx = blockIdx.x * 256 + threadIdx.x;
  if (idx >= NM * NN * NF) return;
  int c = idx & (NF - 1);
  int m = idx / (NN * NF);
  aggr[idx] = bias[m * NF + c];
}

__global__ void k_init_small(unsigned* __restrict__ mx, float* __restrict__ denom,
                             float* __restrict__ wsum) {
  int idx = blockIdx.x * 256 + threadIdx.x;
  if (idx < NM * NN * NH) { mx[idx] = 0u; denom[idx] = 0.0f; }
  if (idx < 8) wsum[idx] = 0.0f;
}

// ---- ft = h @ fc_W (viewed as [20000,256] x [256,384]) ----
__global__ __launch_bounds__(256) void k_gemm(const float* __restrict__ A,
                                              const float* __restrict__ W,
                                              float* __restrict__ ft) {
  __shared__ float As[16][65];
  __shared__ float Bs[16][64];
  const int row0 = blockIdx.x * 64;
  const int c0 = blockIdx.y * 64;       // 0..320, one metapath per tile
  const int m = c0 >> 7;
  const int cin = c0 & 127;
  const int tid = threadIdx.x;
  const int tx = tid & 15, ty = tid >> 4;
  const float* Wm = W + m * (NIN * NF);
  float acc[4][4] = {};
  for (int k0 = 0; k0 < NIN; k0 += 16) {
    int r = tid >> 2;
    int kq = (tid & 3) << 2;
    int gr = row0 + r;
    float4 av = make_float4(0.f, 0.f, 0.f, 0.f);
    if (gr < NN) av = *(const float4*)(A + gr * NIN + k0 + kq);
    As[kq + 0][r] = av.x; As[kq + 1][r] = av.y;
    As[kq + 2][r] = av.z; As[kq + 3][r] = av.w;
    int kb = tid >> 4;
    int cq = (tid & 15) << 2;
    *(float4*)&Bs[kb][cq] = *(const float4*)(Wm + (k0 + kb) * NF + cin + cq);
    __syncthreads();
#pragma unroll
    for (int k = 0; k < 16; ++k) {
      float a[4], b[4];
#pragma unroll
      for (int i = 0; i < 4; ++i) a[i] = As[k][ty * 4 + i];
#pragma unroll
      for (int j = 0; j < 4; ++j) b[j] = Bs[k][tx * 4 + j];
#pragma unroll
      for (int i = 0; i < 4; ++i)
#pragma unroll
        for (int j = 0; j < 4; ++j) acc[i][j] = fmaf(a[i], b[j], acc[i][j]);
    }
    __syncthreads();
  }
#pragma unroll
  for (int i = 0; i < 4; ++i) {
    int gr = row0 + ty * 4 + i;
    if (gr < NN) {
      float4 v = make_float4(acc[i][0], acc[i][1], acc[i][2], acc[i][3]);
      *(float4*)(ft + (m * NN + gr) * NF + cin + tx * 4) = v;
    }
  }
}

// ---- el/er: per (m,n,h) dot over D=16 ----
__global__ void k_elr(const float* __restrict__ ft, const float* __restrict__ al,
                      const float* __restrict__ ar, float* __restrict__ el,
                      float* __restrict__ er) {
  int idx = blockIdx.x * 256 + threadIdx.x;
  if (idx >= NM * NN * NH) return;
  int h = idx & 7;
  int nm = idx >> 3;                 // m*NN + n
  int m = nm / NN;
  const float* f = ft + nm * NF + h * HD;
  const float* alp = al + (m * NH + h) * HD;
  const float* arp = ar + (m * NH + h) * HD;
  float sl = 0.f, sr = 0.f;
#pragma unroll
  for (int d = 0; d < HD; ++d) {
    float fv = f[d];
    sl = fmaf(fv, alp[d], sl);
    sr = fmaf(fv, arp[d], sr);
  }
  el[idx] = sl;
  er[idx] = sr;
}

// ---- pass 1: segment max per (dst, head) ----
__global__ void k_edge_max(const int* __restrict__ src, const int* __restrict__ dst,
                           const float* __restrict__ ew, const float* __restrict__ el,
                           const float* __restrict__ er, unsigned* __restrict__ mx) {
  int idx = blockIdx.x * 256 + threadIdx.x;
  if (idx >= NM * NE) return;
  int m = idx / NE;
  int s = src[idx], d = dst[idx];
  float w = ew[idx];
  const float* lp = el + (m * NN + s) * NH;
  const float* rp = er + (m * NN + d) * NH;
  unsigned* mp = mx + (m * NN + d) * NH;
  float4 l0 = *(const float4*)(lp),     l1 = *(const float4*)(lp + 4);
  float4 r0 = *(const float4*)(rp),     r1 = *(const float4*)(rp + 4);
  float xs[8] = { (l0.x + r0.x) * w, (l0.y + r0.y) * w, (l0.z + r0.z) * w, (l0.w + r0.w) * w,
                  (l1.x + r1.x) * w, (l1.y + r1.y) * w, (l1.z + r1.z) * w, (l1.w + r1.w) * w };
#pragma unroll
  for (int h = 0; h < NH; ++h) {
    float x = xs[h];
    x = x > 0.f ? x : 0.2f * x;
    atomicMax(mp + h, enc_f(x));
  }
}

// ---- pass 2: denom ----
__global__ void k_edge_denom(const int* __restrict__ src, const int* __restrict__ dst,
                             const float* __restrict__ ew, const float* __restrict__ el,
                             const float* __restrict__ er, const unsigned* __restrict__ mx,
                             float* __restrict__ denom) {
  int idx = blockIdx.x * 256 + threadIdx.x;
  if (idx >= NM * NE) return;
  int m = idx / NE;
  int s = src[idx], d = dst[idx];
  float w = ew[idx];
  const float* lp = el + (m * NN + s) * NH;
  const float* rp = er + (m * NN + d) * NH;
  const unsigned* mp = mx + (m * NN + d) * NH;
  float* dp = denom + (m * NN + d) * NH;
  float4 l0 = *(const float4*)(lp),     l1 = *(const float4*)(lp + 4);
  float4 r0 = *(const float4*)(rp),     r1 = *(const float4*)(rp + 4);
  float xs[8] = { (l0.x + r0.x) * w, (l0.y + r0.y) * w, (l0.z + r0.z) * w, (l0.w + r0.w) * w,
                  (l1.x + r1.x) * w, (l1.y + r1.y) * w, (l1.z + r1.z) * w, (l1.w + r1.w) * w };
#pragma unroll
  for (int h = 0; h < NH; ++h) {
    float x = xs[h];
    x = x > 0.f ? x : 0.2f * x;
    float ex = expf(x - dec_f(mp[h]));
    atomAddF(dp + h, ex);
  }
}

// ---- pass 3: aggr[dst] += a * ft[src]; 32 lanes per edge, 4 floats each ----
__global__ void k_edge_aggr(const int* __restrict__ src, const int* __restrict__ dst,
                            const float* __restrict__ ew, const float* __restrict__ el,
                            const float* __restrict__ er, const unsigned* __restrict__ mx,
                            const float* __restrict__ denom, const float* __restrict__ ft,
                            float* __restrict__ aggr) {
  int gid = blockIdx.x * 256 + threadIdx.x;
  int lane = gid & 31;
  int idx = gid >> 5;                 // m*NE + e
  if (idx >= NM * NE) return;
  int m = idx / NE;
  int s = src[idx], d = dst[idx];
  float w = ew[idx];
  int h = lane >> 2;
  int db = (m * NN + d) * NH + h;
  int sb = (m * NN + s) * NH + h;
  float x = (el[sb] + er[db]) * w;
  x = x > 0.f ? x : 0.2f * x;
  float a = expf(x - dec_f(mx[db])) / denom[db];
  int c = lane << 2;
  const float4 fv = *(const float4*)(ft + (m * NN + s) * NF + c);
  float* op = aggr + (m * NN + d) * NF + c;
  atomAddF(op + 0, a * fv.x);
  atomAddF(op + 1, a * fv.y);
  atomAddF(op + 2, a * fv.z);
  atomAddF(op + 3, a * fv.w);
}

// ---- elu in place: aggr -> z ----
__global__ void k_elu(float* __restrict__ z) {
  int idx = blockIdx.x * 256 + threadIdx.x;
  if (idx >= NM * NN * NF) return;
  float v = z[idx];
  z[idx] = v > 0.f ? v : expf(v) - 1.f;
}

// ---- semantic: wsum[m] = sum_n w2 . tanh(z[n,m,:] @ W1 + b1), as a tiled GEMM ----
__global__ __launch_bounds__(256) void k_semgemm(const float* __restrict__ Z,
                                                 const float* __restrict__ W1,
                                                 const float* __restrict__ b1,
                                                 const float* __restrict__ w2,
                                                 float* __restrict__ wsum) {
  __shared__ float As[16][65];
  __shared__ float Bs[16][64];
  const int row0 = blockIdx.x * 64;
  const int c0 = blockIdx.y * 64;
  const int tid = threadIdx.x;
  const int tx = tid & 15, ty = tid >> 4;
  float acc[4][4] = {};
  for (int k0 = 0; k0 < NF; k0 += 16) {
    int r = tid >> 2;
    int kq = (tid & 3) << 2;
    int gr = row0 + r;
    float4 av = make_float4(0.f, 0.f, 0.f, 0.f);
    if (gr < NM * NN) av = *(const float4*)(Z + gr * NF + k0 + kq);
    As[kq + 0][r] = av.x; As[kq + 1][r] = av.y;
    As[kq + 2][r] = av.z; As[kq + 3][r] = av.w;
    int kb = tid >> 4;
    int cq = (tid & 15) << 2;
    *(float4*)&Bs[kb][cq] = *(const float4*)(W1 + (k0 + kb) * NF + c0 + cq);
    __syncthreads();
#pragma unroll
    for (int k = 0; k < 16; ++k) {
      float a[4], b[4];
#pragma unroll
      for (int i = 0; i < 4; ++i) a[i] = As[k][ty * 4 + i];
#pragma unroll
      for (int j = 0; j < 4; ++j) b[j] = Bs[k][tx * 4 + j];
#pragma unroll
      for (int i = 0; i < 4; ++i)
#pragma unroll
        for (int j = 0; j < 4; ++j) acc[i][j] = fmaf(a[i], b[j], acc[i][j]);
    }
    __syncthreads();
  }
  float b1r[4], w2r[4];
#pragma unroll
  for (int j = 0; j < 4; ++j) {
    b1r[j] = b1[c0 + tx * 4 + j];
    w2r[j] = w2[c0 + tx * 4 + j];
  }
#pragma unroll
  for (int i = 0; i < 4; ++i) {
    int gr = row0 + ty * 4 + i;
    float p = 0.f;
#pragma unroll
    for (int j = 0; j < 4; ++j) p += w2r[j] * tanhf(acc[i][j] + b1r[j]);
#pragma unroll
    for (int off = 8; off; off >>= 1) p += __shfl_down(p, off, 16);
    if (tx == 0 && gr < NM * NN) {
      int m = gr / NN;
      atomAddF(wsum + m, p);
    }
  }
}

__global__ void k_beta(const float* __restrict__ wsum, float* __restrict__ beta) {
  if (threadIdx.x == 0 && blockIdx.x == 0) {
    float w0 = wsum[0] / (float)NN;
    float w1 = wsum[1] / (float)NN;
    float w2v = wsum[2] / (float)NN;
    float mx = fmaxf(w0, fmaxf(w1, w2v));
    float e0 = expf(w0 - mx), e1 = expf(w1 - mx), e2 = expf(w2v - mx);
    float s = e0 + e1 + e2;
    beta[0] = e0 / s; beta[1] = e1 / s; beta[2] = e2 / s;
  }
}

__global__ void k_out(const float* __restrict__ z, const float* __restrict__ beta,
                      float* __restrict__ out) {
  int idx = blockIdx.x * 256 + threadIdx.x;
  if (idx >= NN * NF) return;
  out[idx] = beta[0] * z[idx] + beta[1] * z[NN * NF + idx] + beta[2] * z[2 * NN * NF + idx];
}

extern "C" void kernel_launch(void* const* d_in, const int* in_sizes, int n_in,
                              void* d_out, int out_size, void* d_ws, size_t ws_size,
                              hipStream_t stream) {
  (void)in_sizes; (void)n_in; (void)out_size; (void)ws_size;
  const float* h    = (const float*)d_in[0];
  const float* fcW  = (const float*)d_in[1];
  const float* al   = (const float*)d_in[2];
  const float* ar   = (const float*)d_in[3];
  const float* bias = (const float*)d_in[4];
  const float* ew   = (const float*)d_in[5];
  const float* W1   = (const float*)d_in[6];
  const float* b1   = (const float*)d_in[7];
  const float* w2   = (const float*)d_in[8];
  const int* src    = (const int*)d_in[9];
  const int* dst    = (const int*)d_in[10];
  float* out = (float*)d_out;

  float* ws = (float*)d_ws;
  float* ft    = ws;                        // 3*20000*128 = 7,680,000
  float* aggr  = ft + NM * NN * NF;         // 7,680,000 (becomes z after elu)
  float* el    = aggr + NM * NN * NF;       // 480,000
  float* er    = el + NM * NN * NH;         // 480,000
  unsigned* mx = (unsigned*)(er + NM * NN * NH);  // 480,000
  float* denom = (float*)mx + NM * NN * NH; // 480,000
  float* wsum  = denom + NM * NN * NH;      // 8
  float* beta  = wsum + 8;                  // 8

  hipLaunchKernelGGL(k_init_aggr, dim3(30000), dim3(256), 0, stream, bias, aggr);
  hipLaunchKernelGGL(k_init_small, dim3(1875), dim3(256), 0, stream, mx, denom, wsum);
  hipLaunchKernelGGL(k_gemm, dim3(313, 6), dim3(256), 0, stream, h, fcW, ft);
  hipLaunchKernelGGL(k_elr, dim3(1875), dim3(256), 0, stream, ft, al, ar, el, er);
  hipLaunchKernelGGL(k_edge_max, dim3(7500), dim3(256), 0, stream, src, dst, ew, el, er, mx);
  hipLaunchKernelGGL(k_edge_denom, dim3(7500), dim3(256), 0, stream, src, dst, ew, el, er, mx, denom);
  hipLaunchKernelGGL(k_edge_aggr, dim3(240000), dim3(256), 0, stream,
                     src, dst, ew, el, er, mx, denom, ft, aggr);
  hipLaunchKernelGGL(k_elu, dim3(30000), dim3(256), 0, stream, aggr);
  hipLaunchKernelGGL(k_semgemm, dim3(938, 2), dim3(256), 0, stream, aggr, W1, b1, w2, wsum);
  hipLaunchKernelGGL(k_beta, dim3(1), dim3(64), 0, stream, wsum, beta);
  hipLaunchKernelGGL(k_out, dim3(10000), dim3(256), 0, stream, aggr, beta, out);
}

// Round 2
// 2194.344 us; speedup vs baseline: 2.8524x; 2.8524x over previous
//
#include <hip/hip_runtime.h>
#include <math.h>

#define NN 20000
#define NE 640000
#define NIN 256
#define NH 8
#define HD 16
#define NM 3
#define NF 128   // H*D
#define NSEG (NM * NN)
#define SCAN_BLKS ((NSEG + 255) / 256)

__device__ __forceinline__ void atomAddF(float* p, float v) {
  unsafeAtomicAdd(p, v);   // native global_atomic_add_f32 on gfx950
}

// ---- init: zero deg + wsum (ws is poisoned 0xAA) ----
__global__ void k_init(int* __restrict__ deg, float* __restrict__ wsum) {
  int idx = blockIdx.x * 256 + threadIdx.x;
  if (idx < NSEG) deg[idx] = 0;
  if (idx < 8) wsum[idx] = 0.0f;
}

// ---- CSR build: count ----
__global__ void k_count(const int* __restrict__ dst, int* __restrict__ deg) {
  int idx = blockIdx.x * 256 + threadIdx.x;
  if (idx >= NM * NE) return;
  int m = idx / NE;
  atomicAdd(deg + m * NN + dst[idx], 1);
}

// ---- 2-level exclusive scan over deg -> offs ----
__global__ void k_scan1(const int* __restrict__ deg, int* __restrict__ offs,
                        int* __restrict__ bsum) {
  __shared__ int s[256];
  int t = threadIdx.x;
  int seg = blockIdx.x * 256 + t;
  int val = (seg < NSEG) ? deg[seg] : 0;
  s[t] = val;
  __syncthreads();
  for (int o = 1; o < 256; o <<= 1) {
    int x = (t >= o) ? s[t - o] : 0;
    __syncthreads();
    s[t] += x;
    __syncthreads();
  }
  if (seg < NSEG) offs[seg] = s[t] - val;   // exclusive within block
  if (t == 255) bsum[blockIdx.x] = s[t];
}

__global__ void k_scan2(int* __restrict__ bsum, int* __restrict__ offs) {
  __shared__ int s[256];
  int t = threadIdx.x;
  int val = (t < SCAN_BLKS) ? bsum[t] : 0;
  s[t] = val;
  __syncthreads();
  for (int o = 1; o < 256; o <<= 1) {
    int x = (t >= o) ? s[t - o] : 0;
    __syncthreads();
    s[t] += x;
    __syncthreads();
  }
  if (t < SCAN_BLKS) bsum[t] = s[t] - val;  // exclusive
  if (t == SCAN_BLKS - 1) offs[NSEG] = s[t]; // grand total
}

__global__ void k_scan3(int* __restrict__ offs, const int* __restrict__ bsum,
                        int* __restrict__ cursor) {
  int seg = blockIdx.x * 256 + threadIdx.x;
  if (seg >= NSEG) return;
  int o = offs[seg] + bsum[blockIdx.x];
  offs[seg] = o;
  cursor[seg] = o;
}

// ---- CSR fill ----
__global__ void k_fill(const int* __restrict__ dst, int* __restrict__ cursor,
                       int* __restrict__ eidx) {
  int idx = blockIdx.x * 256 + threadIdx.x;
  if (idx >= NM * NE) return;
  int m = idx / NE;
  int pos = atomicAdd(cursor + m * NN + dst[idx], 1);
  eidx[pos] = idx;   // global edge id m*NE+e
}

// ---- ft = h @ fc_W (viewed as [20000,256] x [256,384]) ----
__global__ __launch_bounds__(256) void k_gemm(const float* __restrict__ A,
                                              const float* __restrict__ W,
                                              float* __restrict__ ft) {
  __shared__ float As[16][65];
  __shared__ float Bs[16][64];
  const int row0 = blockIdx.x * 64;
  const int c0 = blockIdx.y * 64;       // 0..320, one metapath per tile
  const int m = c0 >> 7;
  const int cin = c0 & 127;
  const int tid = threadIdx.x;
  const int tx = tid & 15, ty = tid >> 4;
  const float* Wm = W + m * (NIN * NF);
  float acc[4][4] = {};
  for (int k0 = 0; k0 < NIN; k0 += 16) {
    int r = tid >> 2;
    int kq = (tid & 3) << 2;
    int gr = row0 + r;
    float4 av = make_float4(0.f, 0.f, 0.f, 0.f);
    if (gr < NN) av = *(const float4*)(A + gr * NIN + k0 + kq);
    As[kq + 0][r] = av.x; As[kq + 1][r] = av.y;
    As[kq + 2][r] = av.z; As[kq + 3][r] = av.w;
    int kb = tid >> 4;
    int cq = (tid & 15) << 2;
    *(float4*)&Bs[kb][cq] = *(const float4*)(Wm + (k0 + kb) * NF + cin + cq);
    __syncthreads();
#pragma unroll
    for (int k = 0; k < 16; ++k) {
      float a[4], b[4];
#pragma unroll
      for (int i = 0; i < 4; ++i) a[i] = As[k][ty * 4 + i];
#pragma unroll
      for (int j = 0; j < 4; ++j) b[j] = Bs[k][tx * 4 + j];
#pragma unroll
      for (int i = 0; i < 4; ++i)
#pragma unroll
        for (int j = 0; j < 4; ++j) acc[i][j] = fmaf(a[i], b[j], acc[i][j]);
    }
    __syncthreads();
  }
#pragma unroll
  for (int i = 0; i < 4; ++i) {
    int gr = row0 + ty * 4 + i;
    if (gr < NN) {
      float4 v = make_float4(acc[i][0], acc[i][1], acc[i][2], acc[i][3]);
      *(float4*)(ft + (m * NN + gr) * NF + cin + tx * 4) = v;
    }
  }
}

// ---- el/er: per (m,n,h) dot over D=16 ----
__global__ void k_elr(const float* __restrict__ ft, const float* __restrict__ al,
                      const float* __restrict__ ar, float* __restrict__ el,
                      float* __restrict__ er) {
  int idx = blockIdx.x * 256 + threadIdx.x;
  if (idx >= NM * NN * NH) return;
  int h = idx & 7;
  int nm = idx >> 3;                 // m*NN + n
  int m = nm / NN;
  const float* f = ft + nm * NF + h * HD;
  const float* alp = al + (m * NH + h) * HD;
  const float* arp = ar + (m * NH + h) * HD;
  float sl = 0.f, sr = 0.f;
#pragma unroll
  for (int d = 0; d < HD; ++d) {
    float fv = f[d];
    sl = fmaf(fv, alp[d], sl);
    sr = fmaf(fv, arp[d], sr);
  }
  el[idx] = sl;
  er[idx] = sr;
}

// ---- fused per-dst softmax + aggregation: one wave per (m, dst) ----
__global__ __launch_bounds__(256) void k_aggr_csr(
    const int* __restrict__ offs, const int* __restrict__ eidx,
    const int* __restrict__ src, const float* __restrict__ ew,
    const float* __restrict__ el, const float* __restrict__ er,
    const float* __restrict__ ft, const float* __restrict__ bias,
    float* __restrict__ aggr) {
  int wid = (blockIdx.x * 256 + threadIdx.x) >> 6;   // wave id == segment id
  int lane = threadIdx.x & 63;
  if (wid >= NSEG) return;
  int m = wid / NN;
  int beg = offs[wid], end = offs[wid + 1];
  int h = lane & 7, eg = lane >> 3;
  float er_h = er[wid * NH + h];
  const float* elm = el + (size_t)m * NN * NH;
  const float* ftm = ft + (size_t)m * NN * NF;

  // phase 1: online (max, sum) over this segment's edges, 8 edges x 8 heads
  float mx = -1e30f, sm = 0.f;
  for (int i = beg + eg; i < end; i += 8) {
    int eid = eidx[i];
    int s = src[eid];
    float w = ew[eid];
    float x = (elm[s * NH + h] + er_h) * w;
    x = x > 0.f ? x : 0.2f * x;
    float nm2 = fmaxf(mx, x);
    sm = sm * __expf(mx - nm2) + __expf(x - nm2);
    mx = nm2;
  }
#pragma unroll
  for (int mask = 8; mask <= 32; mask <<= 1) {
    float omx = __shfl_xor(mx, mask);
    float osm = __shfl_xor(sm, mask);
    float nm2 = fmaxf(mx, omx);
    sm = sm * __expf(mx - nm2) + osm * __expf(omx - nm2);
    mx = nm2;
  }

  // phase 2: accumulate a * ft[src]; lane owns floats [2*lane, 2*lane+1]
  int h2 = lane >> 3;                  // head of my 2 floats
  float mxh = __shfl(mx, h2);
  float inv = 1.f / __shfl(sm, h2);
  float er2 = __shfl(er_h, h2);
  float2 acc = make_float2(0.f, 0.f);
  for (int i = beg; i < end; ++i) {
    int eid = eidx[i];
    int s = src[eid];
    float w = ew[eid];
    float x = (elm[s * NH + h2] + er2) * w;
    x = x > 0.f ? x : 0.2f * x;
    float a = __expf(x - mxh) * inv;
    const float2 f = *(const float2*)(ftm + s * NF + lane * 2);
    acc.x = fmaf(a, f.x, acc.x);
    acc.y = fmaf(a, f.y, acc.y);
  }
  float ox = acc.x + bias[m * NF + lane * 2];
  float oy = acc.y + bias[m * NF + lane * 2 + 1];
  ox = ox > 0.f ? ox : __expf(ox) - 1.f;
  oy = oy > 0.f ? oy : __expf(oy) - 1.f;
  *(float2*)(aggr + (size_t)wid * NF + lane * 2) = make_float2(ox, oy);
}

// ---- semantic: wsum[m] = sum_n w2 . tanh(z[n,m,:] @ W1 + b1) ----
__global__ __launch_bounds__(256) void k_semgemm(const float* __restrict__ Z,
                                                 const float* __restrict__ W1,
                                                 const float* __restrict__ b1,
                                                 const float* __restrict__ w2,
                                                 float* __restrict__ wsum) {
  __shared__ float As[16][65];
  __shared__ float Bs[16][64];
  const int row0 = blockIdx.x * 64;
  const int c0 = blockIdx.y * 64;
  const int tid = threadIdx.x;
  const int tx = tid & 15, ty = tid >> 4;
  float acc[4][4] = {};
  for (int k0 = 0; k0 < NF; k0 += 16) {
    int r = tid >> 2;
    int kq = (tid & 3) << 2;
    int gr = row0 + r;
    float4 av = make_float4(0.f, 0.f, 0.f, 0.f);
    if (gr < NSEG) av = *(const float4*)(Z + gr * NF + k0 + kq);
    As[kq + 0][r] = av.x; As[kq + 1][r] = av.y;
    As[kq + 2][r] = av.z; As[kq + 3][r] = av.w;
    int kb = tid >> 4;
    int cq = (tid & 15) << 2;
    *(float4*)&Bs[kb][cq] = *(const float4*)(W1 + (k0 + kb) * NF + c0 + cq);
    __syncthreads();
#pragma unroll
    for (int k = 0; k < 16; ++k) {
      float a[4], b[4];
#pragma unroll
      for (int i = 0; i < 4; ++i) a[i] = As[k][ty * 4 + i];
#pragma unroll
      for (int j = 0; j < 4; ++j) b[j] = Bs[k][tx * 4 + j];
#pragma unroll
      for (int i = 0; i < 4; ++i)
#pragma unroll
        for (int j = 0; j < 4; ++j) acc[i][j] = fmaf(a[i], b[j], acc[i][j]);
    }
    __syncthreads();
  }
  float b1r[4], w2r[4];
#pragma unroll
  for (int j = 0; j < 4; ++j) {
    b1r[j] = b1[c0 + tx * 4 + j];
    w2r[j] = w2[c0 + tx * 4 + j];
  }
#pragma unroll
  for (int i = 0; i < 4; ++i) {
    int gr = row0 + ty * 4 + i;
    float p = 0.f;
#pragma unroll
    for (int j = 0; j < 4; ++j) p += w2r[j] * tanhf(acc[i][j] + b1r[j]);
#pragma unroll
    for (int off = 8; off; off >>= 1) p += __shfl_down(p, off, 16);
    if (tx == 0 && gr < NSEG) {
      int m = gr / NN;
      atomAddF(wsum + m, p);
    }
  }
}

__global__ void k_beta(const float* __restrict__ wsum, float* __restrict__ beta) {
  if (threadIdx.x == 0 && blockIdx.x == 0) {
    float w0 = wsum[0] / (float)NN;
    float w1 = wsum[1] / (float)NN;
    float w2v = wsum[2] / (float)NN;
    float mx = fmaxf(w0, fmaxf(w1, w2v));
    float e0 = expf(w0 - mx), e1 = expf(w1 - mx), e2 = expf(w2v - mx);
    float s = e0 + e1 + e2;
    beta[0] = e0 / s; beta[1] = e1 / s; beta[2] = e2 / s;
  }
}

__global__ void k_out(const float* __restrict__ z, const float* __restrict__ beta,
                      float* __restrict__ out) {
  int idx = blockIdx.x * 256 + threadIdx.x;
  if (idx >= NN * NF) return;
  out[idx] = beta[0] * z[idx] + beta[1] * z[NN * NF + idx] + beta[2] * z[2 * NN * NF + idx];
}

extern "C" void kernel_launch(void* const* d_in, const int* in_sizes, int n_in,
                              void* d_out, int out_size, void* d_ws, size_t ws_size,
                              hipStream_t stream) {
  (void)in_sizes; (void)n_in; (void)out_size; (void)ws_size;
  const float* h    = (const float*)d_in[0];
  const float* fcW  = (const float*)d_in[1];
  const float* al   = (const float*)d_in[2];
  const float* ar   = (const float*)d_in[3];
  const float* bias = (const float*)d_in[4];
  const float* ew   = (const float*)d_in[5];
  const float* W1   = (const float*)d_in[6];
  const float* b1   = (const float*)d_in[7];
  const float* w2   = (const float*)d_in[8];
  const int* src    = (const int*)d_in[9];
  const int* dst    = (const int*)d_in[10];
  float* out = (float*)d_out;

  float* ws = (float*)d_ws;
  float* ft    = ws;                          // 7,680,000 f
  float* aggr  = ft + NM * NN * NF;           // 7,680,000 f (z after fuse)
  float* el    = aggr + NM * NN * NF;         // 480,000 f
  float* er    = el + NM * NN * NH;           // 480,000 f
  int* deg     = (int*)(er + NM * NN * NH);   // 60,000 i (becomes cursor)
  int* offs    = deg + NSEG;                  // 60,001 i
  int* bsum    = offs + NSEG + 1;             // 256 i
  int* eidx    = bsum + 256;                  // 1,920,000 i
  float* wsum  = (float*)(eidx + NM * NE);    // 8 f
  float* beta  = wsum + 8;                    // 8 f

  hipLaunchKernelGGL(k_init, dim3(SCAN_BLKS), dim3(256), 0, stream, deg, wsum);
  hipLaunchKernelGGL(k_count, dim3(7500), dim3(256), 0, stream, dst, deg);
  hipLaunchKernelGGL(k_scan1, dim3(SCAN_BLKS), dim3(256), 0, stream, deg, offs, bsum);
  hipLaunchKernelGGL(k_scan2, dim3(1), dim3(256), 0, stream, bsum, offs);
  hipLaunchKernelGGL(k_scan3, dim3(SCAN_BLKS), dim3(256), 0, stream, offs, bsum, deg);
  hipLaunchKernelGGL(k_fill, dim3(7500), dim3(256), 0, stream, dst, deg, eidx);
  hipLaunchKernelGGL(k_gemm, dim3(313, 6), dim3(256), 0, stream, h, fcW, ft);
  hipLaunchKernelGGL(k_elr, dim3(1875), dim3(256), 0, stream, ft, al, ar, el, er);
  hipLaunchKernelGGL(k_aggr_csr, dim3(15000), dim3(256), 0, stream,
                     offs, eidx, src, ew, el, er, ft, bias, aggr);
  hipLaunchKernelGGL(k_semgemm, dim3(938, 2), dim3(256), 0, stream, aggr, W1, b1, w2, wsum);
  hipLaunchKernelGGL(k_beta, dim3(1), dim3(64), 0, stream, wsum, beta);
  hipLaunchKernelGGL(k_out, dim3(10000), dim3(256), 0, stream, aggr, beta, out);
}

// Round 3
// 695.606 us; speedup vs baseline: 8.9980x; 3.1546x over previous
//
#include <hip/hip_runtime.h>
#include <math.h>

#define NN 20000
#define NE 640000
#define NIN 256
#define NH 8
#define HD 16
#define NM 3
#define NF 128   // H*D
#define NSEG (NM * NN)
#define SCAN_BLKS ((NSEG + 255) / 256)

__device__ __forceinline__ void atomAddF(float* p, float v) {
  unsafeAtomicAdd(p, v);   // native global_atomic_add_f32 on gfx950
}

// ---- init: zero deg + wsum (ws is poisoned 0xAA) ----
__global__ void k_init(int* __restrict__ deg, float* __restrict__ wsum) {
  int idx = blockIdx.x * 256 + threadIdx.x;
  if (idx < NSEG) deg[idx] = 0;
  if (idx < 8) wsum[idx] = 0.0f;
}

// ---- CSR build: count ----
__global__ void k_count(const int* __restrict__ dst, int* __restrict__ deg) {
  int idx = blockIdx.x * 256 + threadIdx.x;
  if (idx >= NM * NE) return;
  int m = idx / NE;
  atomicAdd(deg + m * NN + dst[idx], 1);
}

// ---- 2-level exclusive scan over deg -> offs ----
__global__ void k_scan1(const int* __restrict__ deg, int* __restrict__ offs,
                        int* __restrict__ bsum) {
  __shared__ int s[256];
  int t = threadIdx.x;
  int seg = blockIdx.x * 256 + t;
  int val = (seg < NSEG) ? deg[seg] : 0;
  s[t] = val;
  __syncthreads();
  for (int o = 1; o < 256; o <<= 1) {
    int x = (t >= o) ? s[t - o] : 0;
    __syncthreads();
    s[t] += x;
    __syncthreads();
  }
  if (seg < NSEG) offs[seg] = s[t] - val;   // exclusive within block
  if (t == 255) bsum[blockIdx.x] = s[t];
}

__global__ void k_scan2(int* __restrict__ bsum, int* __restrict__ offs) {
  __shared__ int s[256];
  int t = threadIdx.x;
  int val = (t < SCAN_BLKS) ? bsum[t] : 0;
  s[t] = val;
  __syncthreads();
  for (int o = 1; o < 256; o <<= 1) {
    int x = (t >= o) ? s[t - o] : 0;
    __syncthreads();
    s[t] += x;
    __syncthreads();
  }
  if (t < SCAN_BLKS) bsum[t] = s[t] - val;  // exclusive
  if (t == SCAN_BLKS - 1) offs[NSEG] = s[t]; // grand total
}

__global__ void k_scan3(int* __restrict__ offs, const int* __restrict__ bsum,
                        int* __restrict__ cursor) {
  int seg = blockIdx.x * 256 + threadIdx.x;
  if (seg >= NSEG) return;
  int o = offs[seg] + bsum[blockIdx.x];
  offs[seg] = o;
  cursor[seg] = o;
}

// ---- CSR fill ----
__global__ void k_fill(const int* __restrict__ dst, int* __restrict__ cursor,
                       int* __restrict__ eidx) {
  int idx = blockIdx.x * 256 + threadIdx.x;
  if (idx >= NM * NE) return;
  int m = idx / NE;
  int pos = atomicAdd(cursor + m * NN + dst[idx], 1);
  eidx[pos] = idx;   // global edge id m*NE+e
}

// ---- ft = h @ fc_W (viewed as [20000,256] x [256,384]) ----
__global__ __launch_bounds__(256) void k_gemm(const float* __restrict__ A,
                                              const float* __restrict__ W,
                                              float* __restrict__ ft) {
  __shared__ float As[16][65];
  __shared__ float Bs[16][64];
  const int row0 = blockIdx.x * 64;
  const int c0 = blockIdx.y * 64;       // 0..320, one metapath per tile
  const int m = c0 >> 7;
  const int cin = c0 & 127;
  const int tid = threadIdx.x;
  const int tx = tid & 15, ty = tid >> 4;
  const float* Wm = W + m * (NIN * NF);
  float acc[4][4] = {};
  for (int k0 = 0; k0 < NIN; k0 += 16) {
    int r = tid >> 2;
    int kq = (tid & 3) << 2;
    int gr = row0 + r;
    float4 av = make_float4(0.f, 0.f, 0.f, 0.f);
    if (gr < NN) av = *(const float4*)(A + gr * NIN + k0 + kq);
    As[kq + 0][r] = av.x; As[kq + 1][r] = av.y;
    As[kq + 2][r] = av.z; As[kq + 3][r] = av.w;
    int kb = tid >> 4;
    int cq = (tid & 15) << 2;
    *(float4*)&Bs[kb][cq] = *(const float4*)(Wm + (k0 + kb) * NF + cin + cq);
    __syncthreads();
#pragma unroll
    for (int k = 0; k < 16; ++k) {
      float a[4], b[4];
#pragma unroll
      for (int i = 0; i < 4; ++i) a[i] = As[k][ty * 4 + i];
#pragma unroll
      for (int j = 0; j < 4; ++j) b[j] = Bs[k][tx * 4 + j];
#pragma unroll
      for (int i = 0; i < 4; ++i)
#pragma unroll
        for (int j = 0; j < 4; ++j) acc[i][j] = fmaf(a[i], b[j], acc[i][j]);
    }
    __syncthreads();
  }
#pragma unroll
  for (int i = 0; i < 4; ++i) {
    int gr = row0 + ty * 4 + i;
    if (gr < NN) {
      float4 v = make_float4(acc[i][0], acc[i][1], acc[i][2], acc[i][3]);
      *(float4*)(ft + (m * NN + gr) * NF + cin + tx * 4) = v;
    }
  }
}

// ---- el/er: per (m,n,h) dot over D=16 ----
__global__ void k_elr(const float* __restrict__ ft, const float* __restrict__ al,
                      const float* __restrict__ ar, float* __restrict__ el,
                      float* __restrict__ er) {
  int idx = blockIdx.x * 256 + threadIdx.x;
  if (idx >= NM * NN * NH) return;
  int h = idx & 7;
  int nm = idx >> 3;                 // m*NN + n
  int m = nm / NN;
  const float* f = ft + nm * NF + h * HD;
  const float* alp = al + (m * NH + h) * HD;
  const float* arp = ar + (m * NH + h) * HD;
  float sl = 0.f, sr = 0.f;
#pragma unroll
  for (int d = 0; d < HD; ++d) {
    float fv = f[d];
    sl = fmaf(fv, alp[d], sl);
    sr = fmaf(fv, arp[d], sr);
  }
  el[idx] = sl;
  er[idx] = sr;
}

// ---- fused per-dst softmax + aggregation: one wave per (m, dst) ----
__global__ __launch_bounds__(256) void k_aggr_csr(
    const int* __restrict__ offs, const int* __restrict__ eidx,
    const int* __restrict__ src, const float* __restrict__ ew,
    const float* __restrict__ el, const float* __restrict__ er,
    const float* __restrict__ ft, const float* __restrict__ bias,
    float* __restrict__ aggr) {
  int wid = (blockIdx.x * 256 + threadIdx.x) >> 6;   // wave id == segment id
  int lane = threadIdx.x & 63;
  if (wid >= NSEG) return;
  int m = wid / NN;
  int beg = offs[wid], end = offs[wid + 1];
  int h = lane & 7, eg = lane >> 3;
  float er_h = er[wid * NH + h];
  const float* elm = el + (size_t)m * NN * NH;
  const float* ftm = ft + (size_t)m * NN * NF;

  // phase 1: online (max, sum) over this segment's edges, 8 edges x 8 heads
  float mx = -1e30f, sm = 0.f;
  for (int i = beg + eg; i < end; i += 8) {
    int eid = eidx[i];
    int s = src[eid];
    float w = ew[eid];
    float x = (elm[s * NH + h] + er_h) * w;
    x = x > 0.f ? x : 0.2f * x;
    float nm2 = fmaxf(mx, x);
    sm = sm * __expf(mx - nm2) + __expf(x - nm2);
    mx = nm2;
  }
#pragma unroll
  for (int mask = 8; mask <= 32; mask <<= 1) {
    float omx = __shfl_xor(mx, mask);
    float osm = __shfl_xor(sm, mask);
    float nm2 = fmaxf(mx, omx);
    sm = sm * __expf(mx - nm2) + osm * __expf(omx - nm2);
    mx = nm2;
  }

  // phase 2: accumulate a * ft[src]; lane owns floats [2*lane, 2*lane+1]
  int h2 = lane >> 3;                  // head of my 2 floats
  float mxh = __shfl(mx, h2);
  float inv = 1.f / __shfl(sm, h2);
  float er2 = __shfl(er_h, h2);
  float2 acc = make_float2(0.f, 0.f);
  for (int i = beg; i < end; ++i) {
    int eid = eidx[i];
    int s = src[eid];
    float w = ew[eid];
    float x = (elm[s * NH + h2] + er2) * w;
    x = x > 0.f ? x : 0.2f * x;
    float a = __expf(x - mxh) * inv;
    const float2 f = *(const float2*)(ftm + s * NF + lane * 2);
    acc.x = fmaf(a, f.x, acc.x);
    acc.y = fmaf(a, f.y, acc.y);
  }
  float ox = acc.x + bias[m * NF + lane * 2];
  float oy = acc.y + bias[m * NF + lane * 2 + 1];
  ox = ox > 0.f ? ox : __expf(ox) - 1.f;
  oy = oy > 0.f ? oy : __expf(oy) - 1.f;
  *(float2*)(aggr + (size_t)wid * NF + lane * 2) = make_float2(ox, oy);
}

// ---- semantic: wsum[m] = sum_n w2 . tanh(z[n,m,:] @ W1 + b1) ----
// Block-level reduction into LDS, then <=3 global atomics per block.
__global__ __launch_bounds__(256) void k_semgemm(const float* __restrict__ Z,
                                                 const float* __restrict__ W1,
                                                 const float* __restrict__ b1,
                                                 const float* __restrict__ w2,
                                                 float* __restrict__ wsum) {
  __shared__ float As[16][65];
  __shared__ float Bs[16][64];
  __shared__ float msum[NM];
  const int row0 = blockIdx.x * 64;
  const int c0 = blockIdx.y * 64;
  const int tid = threadIdx.x;
  const int tx = tid & 15, ty = tid >> 4;
  if (tid < NM) msum[tid] = 0.f;
  float acc[4][4] = {};
  for (int k0 = 0; k0 < NF; k0 += 16) {
    int r = tid >> 2;
    int kq = (tid & 3) << 2;
    int gr = row0 + r;
    float4 av = make_float4(0.f, 0.f, 0.f, 0.f);
    if (gr < NSEG) av = *(const float4*)(Z + gr * NF + k0 + kq);
    As[kq + 0][r] = av.x; As[kq + 1][r] = av.y;
    As[kq + 2][r] = av.z; As[kq + 3][r] = av.w;
    int kb = tid >> 4;
    int cq = (tid & 15) << 2;
    *(float4*)&Bs[kb][cq] = *(const float4*)(W1 + (k0 + kb) * NF + c0 + cq);
    __syncthreads();
#pragma unroll
    for (int k = 0; k < 16; ++k) {
      float a[4], b[4];
#pragma unroll
      for (int i = 0; i < 4; ++i) a[i] = As[k][ty * 4 + i];
#pragma unroll
      for (int j = 0; j < 4; ++j) b[j] = Bs[k][tx * 4 + j];
#pragma unroll
      for (int i = 0; i < 4; ++i)
#pragma unroll
        for (int j = 0; j < 4; ++j) acc[i][j] = fmaf(a[i], b[j], acc[i][j]);
    }
    __syncthreads();
  }
  float b1r[4], w2r[4];
#pragma unroll
  for (int j = 0; j < 4; ++j) {
    b1r[j] = b1[c0 + tx * 4 + j];
    w2r[j] = w2[c0 + tx * 4 + j];
  }
#pragma unroll
  for (int i = 0; i < 4; ++i) {
    int gr = row0 + ty * 4 + i;
    float p = 0.f;
#pragma unroll
    for (int j = 0; j < 4; ++j) p += w2r[j] * tanhf(acc[i][j] + b1r[j]);
#pragma unroll
    for (int off = 8; off; off >>= 1) p += __shfl_down(p, off, 16);
    if (tx == 0 && gr < NSEG) {
      int m = gr / NN;
      atomicAdd(&msum[m], p);    // LDS atomic, fast
    }
  }
  __syncthreads();
  if (tid < NM) {
    float v = msum[tid];
    if (v != 0.f) atomAddF(wsum + tid, v);
  }
}

__global__ void k_beta(const float* __restrict__ wsum, float* __restrict__ beta) {
  if (threadIdx.x == 0 && blockIdx.x == 0) {
    float w0 = wsum[0] / (float)NN;
    float w1 = wsum[1] / (float)NN;
    float w2v = wsum[2] / (float)NN;
    float mx = fmaxf(w0, fmaxf(w1, w2v));
    float e0 = expf(w0 - mx), e1 = expf(w1 - mx), e2 = expf(w2v - mx);
    float s = e0 + e1 + e2;
    beta[0] = e0 / s; beta[1] = e1 / s; beta[2] = e2 / s;
  }
}

__global__ void k_out(const float* __restrict__ z, const float* __restrict__ beta,
                      float* __restrict__ out) {
  int idx = blockIdx.x * 256 + threadIdx.x;
  if (idx >= NN * NF) return;
  out[idx] = beta[0] * z[idx] + beta[1] * z[NN * NF + idx] + beta[2] * z[2 * NN * NF + idx];
}

extern "C" void kernel_launch(void* const* d_in, const int* in_sizes, int n_in,
                              void* d_out, int out_size, void* d_ws, size_t ws_size,
                              hipStream_t stream) {
  (void)in_sizes; (void)n_in; (void)out_size; (void)ws_size;
  const float* h    = (const float*)d_in[0];
  const float* fcW  = (const float*)d_in[1];
  const float* al   = (const float*)d_in[2];
  const float* ar   = (const float*)d_in[3];
  const float* bias = (const float*)d_in[4];
  const float* ew   = (const float*)d_in[5];
  const float* W1   = (const float*)d_in[6];
  const float* b1   = (const float*)d_in[7];
  const float* w2   = (const float*)d_in[8];
  const int* src    = (const int*)d_in[9];
  const int* dst    = (const int*)d_in[10];
  float* out = (float*)d_out;

  float* ws = (float*)d_ws;
  float* ft    = ws;                          // 7,680,000 f
  float* aggr  = ft + NM * NN * NF;           // 7,680,000 f (z after fuse)
  float* el    = aggr + NM * NN * NF;         // 480,000 f
  float* er    = el + NM * NN * NH;           // 480,000 f
  int* deg     = (int*)(er + NM * NN * NH);   // 60,000 i (becomes cursor)
  int* offs    = deg + NSEG;                  // 60,001 i
  int* bsum    = offs + NSEG + 1;             // 256 i
  int* eidx    = bsum + 256;                  // 1,920,000 i
  float* wsum  = (float*)(eidx + NM * NE);    // 8 f
  float* beta  = wsum + 8;                    // 8 f

  hipLaunchKernelGGL(k_init, dim3(SCAN_BLKS), dim3(256), 0, stream, deg, wsum);
  hipLaunchKernelGGL(k_count, dim3(7500), dim3(256), 0, stream, dst, deg);
  hipLaunchKernelGGL(k_scan1, dim3(SCAN_BLKS), dim3(256), 0, stream, deg, offs, bsum);
  hipLaunchKernelGGL(k_scan2, dim3(1), dim3(256), 0, stream, bsum, offs);
  hipLaunchKernelGGL(k_scan3, dim3(SCAN_BLKS), dim3(256), 0, stream, offs, bsum, deg);
  hipLaunchKernelGGL(k_fill, dim3(7500), dim3(256), 0, stream, dst, deg, eidx);
  hipLaunchKernelGGL(k_gemm, dim3(313, 6), dim3(256), 0, stream, h, fcW, ft);
  hipLaunchKernelGGL(k_elr, dim3(1875), dim3(256), 0, stream, ft, al, ar, el, er);
  hipLaunchKernelGGL(k_aggr_csr, dim3(15000), dim3(256), 0, stream,
                     offs, eidx, src, ew, el, er, ft, bias, aggr);
  hipLaunchKernelGGL(k_semgemm, dim3(938, 2), dim3(256), 0, stream, aggr, W1, b1, w2, wsum);
  hipLaunchKernelGGL(k_beta, dim3(1), dim3(64), 0, stream, wsum, beta);
  hipLaunchKernelGGL(k_out, dim3(10000), dim3(256), 0, stream, aggr, beta, out);
}

// Round 4
// 514.974 us; speedup vs baseline: 12.1542x; 1.3508x over previous
//
#include <hip/hip_runtime.h>
#include <hip/hip_fp16.h>
#include <math.h>

#define NN 20000
#define NE 640000
#define NIN 256
#define NH 8
#define HD 16
#define NM 3
#define NF 128   // H*D
#define NSEG (NM * NN)
#define SCAN_BLKS ((NSEG + 255) / 256)

__device__ __forceinline__ void atomAddF(float* p, float v) {
  unsafeAtomicAdd(p, v);   // native global_atomic_add_f32 on gfx950
}

// ---- init: zero deg + wsum (ws is poisoned 0xAA) ----
__global__ void k_init(int* __restrict__ deg, float* __restrict__ wsum) {
  int idx = blockIdx.x * 256 + threadIdx.x;
  if (idx < NSEG) deg[idx] = 0;
  if (idx < 8) wsum[idx] = 0.0f;
}

// ---- CSR build: count ----
__global__ void k_count(const int* __restrict__ dst, int* __restrict__ deg) {
  int idx = blockIdx.x * 256 + threadIdx.x;
  if (idx >= NM * NE) return;
  int m = idx / NE;
  atomicAdd(deg + m * NN + dst[idx], 1);
}

// ---- 2-level exclusive scan over deg -> offs ----
__global__ void k_scan1(const int* __restrict__ deg, int* __restrict__ offs,
                        int* __restrict__ bsum) {
  __shared__ int s[256];
  int t = threadIdx.x;
  int seg = blockIdx.x * 256 + t;
  int val = (seg < NSEG) ? deg[seg] : 0;
  s[t] = val;
  __syncthreads();
  for (int o = 1; o < 256; o <<= 1) {
    int x = (t >= o) ? s[t - o] : 0;
    __syncthreads();
    s[t] += x;
    __syncthreads();
  }
  if (seg < NSEG) offs[seg] = s[t] - val;   // exclusive within block
  if (t == 255) bsum[blockIdx.x] = s[t];
}

__global__ void k_scan2(int* __restrict__ bsum, int* __restrict__ offs) {
  __shared__ int s[256];
  int t = threadIdx.x;
  int val = (t < SCAN_BLKS) ? bsum[t] : 0;
  s[t] = val;
  __syncthreads();
  for (int o = 1; o < 256; o <<= 1) {
    int x = (t >= o) ? s[t - o] : 0;
    __syncthreads();
    s[t] += x;
    __syncthreads();
  }
  if (t < SCAN_BLKS) bsum[t] = s[t] - val;  // exclusive
  if (t == SCAN_BLKS - 1) offs[NSEG] = s[t]; // grand total
}

__global__ void k_scan3(int* __restrict__ offs, const int* __restrict__ bsum,
                        int* __restrict__ cursor) {
  int seg = blockIdx.x * 256 + threadIdx.x;
  if (seg >= NSEG) return;
  int o = offs[seg] + bsum[blockIdx.x];
  offs[seg] = o;
  cursor[seg] = o;
}

// ---- CSR fill ----
__global__ void k_fill(const int* __restrict__ dst, int* __restrict__ cursor,
                       int* __restrict__ eidx) {
  int idx = blockIdx.x * 256 + threadIdx.x;
  if (idx >= NM * NE) return;
  int m = idx / NE;
  int pos = atomicAdd(cursor + m * NN + dst[idx], 1);
  eidx[pos] = idx;   // global edge id m*NE+e
}

// ---- ft = h @ fc_W; optionally also emit fp16 copy for the gather pass ----
template <bool WH>
__global__ __launch_bounds__(256) void k_gemm(const float* __restrict__ A,
                                              const float* __restrict__ W,
                                              float* __restrict__ ft,
                                              __half* __restrict__ fth) {
  __shared__ float As[16][65];
  __shared__ float Bs[16][64];
  const int row0 = blockIdx.x * 64;
  const int c0 = blockIdx.y * 64;       // 0..320, one metapath per tile
  const int m = c0 >> 7;
  const int cin = c0 & 127;
  const int tid = threadIdx.x;
  const int tx = tid & 15, ty = tid >> 4;
  const float* Wm = W + m * (NIN * NF);
  float acc[4][4] = {};
  for (int k0 = 0; k0 < NIN; k0 += 16) {
    int r = tid >> 2;
    int kq = (tid & 3) << 2;
    int gr = row0 + r;
    float4 av = make_float4(0.f, 0.f, 0.f, 0.f);
    if (gr < NN) av = *(const float4*)(A + gr * NIN + k0 + kq);
    As[kq + 0][r] = av.x; As[kq + 1][r] = av.y;
    As[kq + 2][r] = av.z; As[kq + 3][r] = av.w;
    int kb = tid >> 4;
    int cq = (tid & 15) << 2;
    *(float4*)&Bs[kb][cq] = *(const float4*)(Wm + (k0 + kb) * NF + cin + cq);
    __syncthreads();
#pragma unroll
    for (int k = 0; k < 16; ++k) {
      float a[4], b[4];
#pragma unroll
      for (int i = 0; i < 4; ++i) a[i] = As[k][ty * 4 + i];
#pragma unroll
      for (int j = 0; j < 4; ++j) b[j] = Bs[k][tx * 4 + j];
#pragma unroll
      for (int i = 0; i < 4; ++i)
#pragma unroll
        for (int j = 0; j < 4; ++j) acc[i][j] = fmaf(a[i], b[j], acc[i][j]);
    }
    __syncthreads();
  }
#pragma unroll
  for (int i = 0; i < 4; ++i) {
    int gr = row0 + ty * 4 + i;
    if (gr < NN) {
      float4 v = make_float4(acc[i][0], acc[i][1], acc[i][2], acc[i][3]);
      *(float4*)(ft + (size_t)(m * NN + gr) * NF + cin + tx * 4) = v;
      if (WH) {
        __half2 p01 = __floats2half2_rn(acc[i][0], acc[i][1]);
        __half2 p23 = __floats2half2_rn(acc[i][2], acc[i][3]);
        uint2 u;
        u.x = *(unsigned*)&p01;
        u.y = *(unsigned*)&p23;
        *(uint2*)(fth + (size_t)(m * NN + gr) * NF + cin + tx * 4) = u;
      }
    }
  }
}

// ---- el/er: per (m,n,h) dot over D=16 ----
__global__ void k_elr(const float* __restrict__ ft, const float* __restrict__ al,
                      const float* __restrict__ ar, float* __restrict__ el,
                      float* __restrict__ er) {
  int idx = blockIdx.x * 256 + threadIdx.x;
  if (idx >= NM * NN * NH) return;
  int h = idx & 7;
  int nm = idx >> 3;                 // m*NN + n
  int m = nm / NN;
  const float* f = ft + (size_t)nm * NF + h * HD;
  const float* alp = al + (m * NH + h) * HD;
  const float* arp = ar + (m * NH + h) * HD;
  float sl = 0.f, sr = 0.f;
#pragma unroll
  for (int d = 0; d < HD; ++d) {
    float fv = f[d];
    sl = fmaf(fv, alp[d], sl);
    sr = fmaf(fv, arp[d], sr);
  }
  el[idx] = sl;
  er[idx] = sr;
}

// ---- fused per-dst ONLINE softmax + aggregation ----
// one wave per (m, dst); 2 edges per iteration (32 lanes/edge, 4 cols/lane)
template <bool USEH>
__global__ __launch_bounds__(256) void k_aggr2(
    const int* __restrict__ offs, const int* __restrict__ eidx,
    const int* __restrict__ src, const float* __restrict__ ew,
    const float* __restrict__ el, const float* __restrict__ er,
    const float* __restrict__ ft, const __half* __restrict__ fth,
    const float* __restrict__ bias, float* __restrict__ aggr) {
  int wid = (blockIdx.x * 256 + threadIdx.x) >> 6;   // wave id == segment id
  int lane = threadIdx.x & 63;
  if (wid >= NSEG) return;
  int m = wid / NN;
  int beg = offs[wid], end = offs[wid + 1];
  int l32 = lane & 31;
  int half = lane >> 5;
  int h2 = l32 >> 2;          // head owning my 4 columns
  int c0 = l32 * 4;           // column base within the 128-wide row
  float er2 = er[wid * NH + h2];
  const float* elm = el + (size_t)m * NN * NH;
  const float* ftm = ft + (size_t)m * NN * NF;
  const __half* fhm = fth + (size_t)m * NN * NF;

  float mx = -1e30f, sm = 0.f;
  float a0 = 0.f, a1 = 0.f, a2 = 0.f, a3 = 0.f;
  for (int i = beg + half; i < end; i += 2) {
    int eid = eidx[i];
    int s = src[eid];
    float w = ew[eid];
    float x = (elm[s * NH + h2] + er2) * w;
    x = x > 0.f ? x : 0.2f * x;
    float nm2 = fmaxf(mx, x);
    float f = __expf(mx - nm2);   // rescale of old state (1 if max unchanged)
    float e = __expf(x - nm2);
    mx = nm2;
    sm = sm * f + e;
    float4 fv;
    if (USEH) {
      const uint2 q = *(const uint2*)(fhm + (size_t)s * NF + c0);
      __half2 h01 = *(__half2*)&q.x;
      __half2 h23 = *(__half2*)&q.y;
      float2 f01 = __half22float2(h01);
      float2 f23 = __half22float2(h23);
      fv = make_float4(f01.x, f01.y, f23.x, f23.y);
    } else {
      fv = *(const float4*)(ftm + (size_t)s * NF + c0);
    }
    a0 = fmaf(e, fv.x, a0 * f);
    a1 = fmaf(e, fv.y, a1 * f);
    a2 = fmaf(e, fv.z, a2 * f);
    a3 = fmaf(e, fv.w, a3 * f);
  }
  // merge the two edge-halves (same columns live in lane l and l+32)
  float omx = __shfl_xor(mx, 32);
  float osm = __shfl_xor(sm, 32);
  float o0 = __shfl_xor(a0, 32), o1 = __shfl_xor(a1, 32);
  float o2 = __shfl_xor(a2, 32), o3 = __shfl_xor(a3, 32);
  float nm2 = fmaxf(mx, omx);
  float f1 = __expf(mx - nm2), f2 = __expf(omx - nm2);
  sm = sm * f1 + osm * f2;
  a0 = a0 * f1 + o0 * f2;
  a1 = a1 * f1 + o1 * f2;
  a2 = a2 * f1 + o2 * f2;
  a3 = a3 * f1 + o3 * f2;
  float inv = sm > 0.f ? 1.f / sm : 0.f;
  if (half == 0) {
    const float4 bv = *(const float4*)(bias + m * NF + c0);
    float q0 = fmaf(a0, inv, bv.x);
    float q1 = fmaf(a1, inv, bv.y);
    float q2 = fmaf(a2, inv, bv.z);
    float q3 = fmaf(a3, inv, bv.w);
    q0 = q0 > 0.f ? q0 : __expf(q0) - 1.f;
    q1 = q1 > 0.f ? q1 : __expf(q1) - 1.f;
    q2 = q2 > 0.f ? q2 : __expf(q2) - 1.f;
    q3 = q3 > 0.f ? q3 : __expf(q3) - 1.f;
    *(float4*)(aggr + (size_t)wid * NF + c0) = make_float4(q0, q1, q2, q3);
  }
}

// ---- semantic: wsum[m] = sum_n w2 . tanh(z[n,m,:] @ W1 + b1) ----
// Block-level reduction into LDS, then <=3 global atomics per block.
__global__ __launch_bounds__(256) void k_semgemm(const float* __restrict__ Z,
                                                 const float* __restrict__ W1,
                                                 const float* __restrict__ b1,
                                                 const float* __restrict__ w2,
                                                 float* __restrict__ wsum) {
  __shared__ float As[16][65];
  __shared__ float Bs[16][64];
  __shared__ float msum[NM];
  const int row0 = blockIdx.x * 64;
  const int c0 = blockIdx.y * 64;
  const int tid = threadIdx.x;
  const int tx = tid & 15, ty = tid >> 4;
  if (tid < NM) msum[tid] = 0.f;
  float acc[4][4] = {};
  for (int k0 = 0; k0 < NF; k0 += 16) {
    int r = tid >> 2;
    int kq = (tid & 3) << 2;
    int gr = row0 + r;
    float4 av = make_float4(0.f, 0.f, 0.f, 0.f);
    if (gr < NSEG) av = *(const float4*)(Z + (size_t)gr * NF + k0 + kq);
    As[kq + 0][r] = av.x; As[kq + 1][r] = av.y;
    As[kq + 2][r] = av.z; As[kq + 3][r] = av.w;
    int kb = tid >> 4;
    int cq = (tid & 15) << 2;
    *(float4*)&Bs[kb][cq] = *(const float4*)(W1 + (k0 + kb) * NF + c0 + cq);
    __syncthreads();
#pragma unroll
    for (int k = 0; k < 16; ++k) {
      float a[4], b[4];
#pragma unroll
      for (int i = 0; i < 4; ++i) a[i] = As[k][ty * 4 + i];
#pragma unroll
      for (int j = 0; j < 4; ++j) b[j] = Bs[k][tx * 4 + j];
#pragma unroll
      for (int i = 0; i < 4; ++i)
#pragma unroll
        for (int j = 0; j < 4; ++j) acc[i][j] = fmaf(a[i], b[j], acc[i][j]);
    }
    __syncthreads();
  }
  float b1r[4], w2r[4];
#pragma unroll
  for (int j = 0; j < 4; ++j) {
    b1r[j] = b1[c0 + tx * 4 + j];
    w2r[j] = w2[c0 + tx * 4 + j];
  }
#pragma unroll
  for (int i = 0; i < 4; ++i) {
    int gr = row0 + ty * 4 + i;
    float p = 0.f;
#pragma unroll
    for (int j = 0; j < 4; ++j) p += w2r[j] * tanhf(acc[i][j] + b1r[j]);
#pragma unroll
    for (int off = 8; off; off >>= 1) p += __shfl_down(p, off, 16);
    if (tx == 0 && gr < NSEG) {
      int m = gr / NN;
      atomicAdd(&msum[m], p);    // LDS atomic, fast
    }
  }
  __syncthreads();
  if (tid < NM) {
    float v = msum[tid];
    if (v != 0.f) atomAddF(wsum + tid, v);
  }
}

__global__ void k_beta(const float* __restrict__ wsum, float* __restrict__ beta) {
  if (threadIdx.x == 0 && blockIdx.x == 0) {
    float w0 = wsum[0] / (float)NN;
    float w1 = wsum[1] / (float)NN;
    float w2v = wsum[2] / (float)NN;
    float mx = fmaxf(w0, fmaxf(w1, w2v));
    float e0 = expf(w0 - mx), e1 = expf(w1 - mx), e2 = expf(w2v - mx);
    float s = e0 + e1 + e2;
    beta[0] = e0 / s; beta[1] = e1 / s; beta[2] = e2 / s;
  }
}

__global__ void k_out(const float* __restrict__ z, const float* __restrict__ beta,
                      float* __restrict__ out) {
  int idx = blockIdx.x * 256 + threadIdx.x;
  if (idx >= NN * NF) return;
  out[idx] = beta[0] * z[idx] + beta[1] * z[NN * NF + idx] + beta[2] * z[2 * NN * NF + idx];
}

extern "C" void kernel_launch(void* const* d_in, const int* in_sizes, int n_in,
                              void* d_out, int out_size, void* d_ws, size_t ws_size,
                              hipStream_t stream) {
  (void)in_sizes; (void)n_in; (void)out_size;
  const float* h    = (const float*)d_in[0];
  const float* fcW  = (const float*)d_in[1];
  const float* al   = (const float*)d_in[2];
  const float* ar   = (const float*)d_in[3];
  const float* bias = (const float*)d_in[4];
  const float* ew   = (const float*)d_in[5];
  const float* W1   = (const float*)d_in[6];
  const float* b1   = (const float*)d_in[7];
  const float* w2   = (const float*)d_in[8];
  const int* src    = (const int*)d_in[9];
  const int* dst    = (const int*)d_in[10];
  float* out = (float*)d_out;

  float* ws = (float*)d_ws;
  float* ft    = ws;                          // 7,680,000 f
  float* aggr  = ft + (size_t)NM * NN * NF;   // 7,680,000 f (z after fuse)
  float* el    = aggr + (size_t)NM * NN * NF; // 480,000 f
  float* er    = el + NM * NN * NH;           // 480,000 f
  int* deg     = (int*)(er + NM * NN * NH);   // 60,000 i (becomes cursor)
  int* offs    = deg + NSEG;                  // 60,001 i
  int* bsum    = offs + NSEG + 1;             // 256 i
  int* eidx    = bsum + 256;                  // 1,920,000 i
  float* wsum  = (float*)(eidx + NM * NE);    // 8 f
  float* beta  = wsum + 8;                    // 8 f
  // fp16 gather copy of ft, 8-byte aligned, at the end of the f32 region
  size_t base_words = ((size_t)(beta + 8 - ws) + 1) & ~(size_t)1;
  __half* fth = (__half*)(ws + base_words);
  size_t need = base_words * 4 + (size_t)NM * NN * NF * sizeof(__half);
  bool useH = ws_size >= need;

  hipLaunchKernelGGL(k_init, dim3(SCAN_BLKS), dim3(256), 0, stream, deg, wsum);
  hipLaunchKernelGGL(k_count, dim3(7500), dim3(256), 0, stream, dst, deg);
  hipLaunchKernelGGL(k_scan1, dim3(SCAN_BLKS), dim3(256), 0, stream, deg, offs, bsum);
  hipLaunchKernelGGL(k_scan2, dim3(1), dim3(256), 0, stream, bsum, offs);
  hipLaunchKernelGGL(k_scan3, dim3(SCAN_BLKS), dim3(256), 0, stream, offs, bsum, deg);
  hipLaunchKernelGGL(k_fill, dim3(7500), dim3(256), 0, stream, dst, deg, eidx);
  if (useH) {
    hipLaunchKernelGGL(k_gemm<true>, dim3(313, 6), dim3(256), 0, stream, h, fcW, ft, fth);
  } else {
    hipLaunchKernelGGL(k_gemm<false>, dim3(313, 6), dim3(256), 0, stream, h, fcW, ft, fth);
  }
  hipLaunchKernelGGL(k_elr, dim3(1875), dim3(256), 0, stream, ft, al, ar, el, er);
  if (useH) {
    hipLaunchKernelGGL(k_aggr2<true>, dim3(15000), dim3(256), 0, stream,
                       offs, eidx, src, ew, el, er, ft, fth, bias, aggr);
  } else {
    hipLaunchKernelGGL(k_aggr2<false>, dim3(15000), dim3(256), 0, stream,
                       offs, eidx, src, ew, el, er, ft, fth, bias, aggr);
  }
  hipLaunchKernelGGL(k_semgemm, dim3(938, 2), dim3(256), 0, stream, aggr, W1, b1, w2, wsum);
  hipLaunchKernelGGL(k_beta, dim3(1), dim3(64), 0, stream, wsum, beta);
  hipLaunchKernelGGL(k_out, dim3(10000), dim3(256), 0, stream, aggr, beta, out);
}

// Round 5
// 513.523 us; speedup vs baseline: 12.1885x; 1.0028x over previous
//
#include <hip/hip_runtime.h>
#include <math.h>

#define NN 20000
#define NE 640000
#define NIN 256
#define NH 8
#define HD 16
#define NM 3
#define NF 128   // H*D
#define HID 128
#define NSEG (NM * NN)
#define SCAN_BLKS ((NSEG + 255) / 256)

typedef __attribute__((ext_vector_type(4))) _Float16 half4;
typedef __attribute__((ext_vector_type(8))) _Float16 half8;
typedef __attribute__((ext_vector_type(4))) float f32x4;

__device__ __forceinline__ void atomAddF(float* p, float v) {
  unsafeAtomicAdd(p, v);   // native global_atomic_add_f32 on gfx950
}

// ---- prep: fp16 conversions + zero deg/wsum (ws is poisoned 0xAA) ----
__global__ void k_prep(const float* __restrict__ h, const float* __restrict__ fcW,
                       const float* __restrict__ W1, _Float16* __restrict__ h16,
                       _Float16* __restrict__ WT, _Float16* __restrict__ W1T,
                       int* __restrict__ deg, float* __restrict__ wsum) {
  int t = blockIdx.x * 256 + threadIdx.x;
  if (t < NN * NIN / 4) {
    float4 v = *(const float4*)(h + 4 * t);
    half4 o = {(_Float16)v.x, (_Float16)v.y, (_Float16)v.z, (_Float16)v.w};
    *(half4*)(h16 + 4 * t) = o;
  }
  if (t < NM * NIN * NF) {              // WT[(m*128+n)*256+k] = fcW[m][k][n]
    int mm = t >> 15;
    int n = (t >> 8) & 127;
    int k = t & 255;
    WT[t] = (_Float16)fcW[(mm << 15) + (k << 7) + n];
  }
  if (t < NF * HID) {                   // W1T[n*128+k] = W1[k][n]
    int n = t >> 7;
    int k = t & 127;
    W1T[t] = (_Float16)W1[k * HID + n];
  }
  if (t < NSEG) deg[t] = 0;
  if (t < 8) wsum[t] = 0.0f;
}

// ---- CSR build: count ----
__global__ void k_count(const int* __restrict__ dst, int* __restrict__ deg) {
  int idx = blockIdx.x * 256 + threadIdx.x;
  if (idx >= NM * NE) return;
  int m = idx / NE;
  atomicAdd(deg + m * NN + dst[idx], 1);
}

// ---- 2-level exclusive scan over deg -> offs ----
__global__ void k_scan1(const int* __restrict__ deg, int* __restrict__ offs,
                        int* __restrict__ bsum) {
  __shared__ int s[256];
  int t = threadIdx.x;
  int seg = blockIdx.x * 256 + t;
  int val = (seg < NSEG) ? deg[seg] : 0;
  s[t] = val;
  __syncthreads();
  for (int o = 1; o < 256; o <<= 1) {
    int x = (t >= o) ? s[t - o] : 0;
    __syncthreads();
    s[t] += x;
    __syncthreads();
  }
  if (seg < NSEG) offs[seg] = s[t] - val;
  if (t == 255) bsum[blockIdx.x] = s[t];
}

__global__ void k_scan2(int* __restrict__ bsum, int* __restrict__ offs) {
  __shared__ int s[256];
  int t = threadIdx.x;
  int val = (t < SCAN_BLKS) ? bsum[t] : 0;
  s[t] = val;
  __syncthreads();
  for (int o = 1; o < 256; o <<= 1) {
    int x = (t >= o) ? s[t - o] : 0;
    __syncthreads();
    s[t] += x;
    __syncthreads();
  }
  if (t < SCAN_BLKS) bsum[t] = s[t] - val;
  if (t == SCAN_BLKS - 1) offs[NSEG] = s[t];
}

__global__ void k_scan3(int* __restrict__ offs, const int* __restrict__ bsum,
                        int* __restrict__ cursor) {
  int seg = blockIdx.x * 256 + threadIdx.x;
  if (seg >= NSEG) return;
  int o = offs[seg] + bsum[blockIdx.x];
  offs[seg] = o;
  cursor[seg] = o;
}

// ---- CSR fill ----
__global__ void k_fill(const int* __restrict__ dst, int* __restrict__ cursor,
                       int* __restrict__ eidx) {
  int idx = blockIdx.x * 256 + threadIdx.x;
  if (idx >= NM * NE) return;
  int m = idx / NE;
  int pos = atomicAdd(cursor + m * NN + dst[idx], 1);
  eidx[pos] = idx;
}

// ---- ft(fp16) = h16 @ WT via mfma_f32_16x16x32_f16, no LDS ----
// grid (ceil(NN/64), 6): y -> (m = y>>1, cin = (y&1)*64). 4 waves, 16 rows each.
__global__ __launch_bounds__(256) void k_gemm_mfma(const _Float16* __restrict__ h16,
                                                   const _Float16* __restrict__ WT,
                                                   _Float16* __restrict__ fth) {
  int tid = threadIdx.x;
  int wave = tid >> 6, lane = tid & 63;
  int l15 = lane & 15, kslot = lane >> 4;
  int m = blockIdx.y >> 1;
  int cin = (blockIdx.y & 1) << 6;
  int rowbase = blockIdx.x * 64 + wave * 16;
  int arow = rowbase + l15;
  bool aok = arow < NN;
  const _Float16* Ap = h16 + (size_t)(aok ? arow : 0) * NIN + kslot * 8;
  const _Float16* Bp = WT + ((size_t)m * NF + cin + l15) * NIN + kslot * 8;
  f32x4 acc0 = {0.f, 0.f, 0.f, 0.f}, acc1 = acc0, acc2 = acc0, acc3 = acc0;
#pragma unroll
  for (int kk = 0; kk < 8; ++kk) {
    int k0 = kk * 32;
    half8 a = {};
    if (aok) a = *(const half8*)(Ap + k0);
    half8 b0 = *(const half8*)(Bp + k0);
    half8 b1 = *(const half8*)(Bp + 16 * NIN + k0);
    half8 b2 = *(const half8*)(Bp + 32 * NIN + k0);
    half8 b3 = *(const half8*)(Bp + 48 * NIN + k0);
    acc0 = __builtin_amdgcn_mfma_f32_16x16x32_f16(a, b0, acc0, 0, 0, 0);
    acc1 = __builtin_amdgcn_mfma_f32_16x16x32_f16(a, b1, acc1, 0, 0, 0);
    acc2 = __builtin_amdgcn_mfma_f32_16x16x32_f16(a, b2, acc2, 0, 0, 0);
    acc3 = __builtin_amdgcn_mfma_f32_16x16x32_f16(a, b3, acc3, 0, 0, 0);
  }
  int orow0 = rowbase + kslot * 4;
#pragma unroll
  for (int j = 0; j < 4; ++j) {
    int r = orow0 + j;
    if (r < NN) {
      _Float16* op = fth + ((size_t)m * NN + r) * NF + cin + l15;
      op[0]  = (_Float16)acc0[j];
      op[16] = (_Float16)acc1[j];
      op[32] = (_Float16)acc2[j];
      op[48] = (_Float16)acc3[j];
    }
  }
}

// ---- el/er: per (m,n,h) dot over D=16, reading fp16 ft ----
__global__ void k_elr(const _Float16* __restrict__ fth, const float* __restrict__ al,
                      const float* __restrict__ ar, float* __restrict__ el,
                      float* __restrict__ er) {
  int idx = blockIdx.x * 256 + threadIdx.x;
  if (idx >= NM * NN * NH) return;
  int h = idx & 7;
  int nm = idx >> 3;
  int m = nm / NN;
  const _Float16* f = fth + (size_t)nm * NF + h * HD;
  half8 v0 = *(const half8*)(f);
  half8 v1 = *(const half8*)(f + 8);
  const float* alp = al + (m * NH + h) * HD;
  const float* arp = ar + (m * NH + h) * HD;
  float sl = 0.f, sr = 0.f;
#pragma unroll
  for (int d = 0; d < 8; ++d) {
    float f0 = (float)v0[d], f1 = (float)v1[d];
    sl = fmaf(f0, alp[d], sl);     sr = fmaf(f0, arp[d], sr);
    sl = fmaf(f1, alp[d + 8], sl); sr = fmaf(f1, arp[d + 8], sr);
  }
  el[idx] = sl;
  er[idx] = sr;
}

// ---- fused per-dst ONLINE softmax + aggregation ----
// one wave per (m, dst); 2 edges/iter (32 lanes/edge, 4 cols/lane, fp16 gather)
__global__ __launch_bounds__(256) void k_aggr2(
    const int* __restrict__ offs, const int* __restrict__ eidx,
    const int* __restrict__ src, const float* __restrict__ ew,
    const float* __restrict__ el, const float* __restrict__ er,
    const _Float16* __restrict__ fth, const float* __restrict__ bias,
    float* __restrict__ aggr, _Float16* __restrict__ zh) {
  int wid = (blockIdx.x * 256 + threadIdx.x) >> 6;
  int lane = threadIdx.x & 63;
  if (wid >= NSEG) return;
  int m = wid / NN;
  int beg = offs[wid], end = offs[wid + 1];
  int l32 = lane & 31;
  int half_ = lane >> 5;
  int h2 = l32 >> 2;
  int c0 = l32 * 4;
  float er2 = er[wid * NH + h2];
  const float* elm = el + (size_t)m * NN * NH;
  const _Float16* fhm = fth + (size_t)m * NN * NF;

  float mx = -1e30f, sm = 0.f;
  float a0 = 0.f, a1 = 0.f, a2 = 0.f, a3 = 0.f;
  for (int i = beg + half_; i < end; i += 2) {
    int eid = eidx[i];
    int s = src[eid];
    float w = ew[eid];
    float x = (elm[s * NH + h2] + er2) * w;
    x = x > 0.f ? x : 0.2f * x;
    float nm2 = fmaxf(mx, x);
    float f = __expf(mx - nm2);
    float e = __expf(x - nm2);
    mx = nm2;
    sm = sm * f + e;
    half4 q = *(const half4*)(fhm + (size_t)s * NF + c0);
    a0 = fmaf(e, (float)q.x, a0 * f);
    a1 = fmaf(e, (float)q.y, a1 * f);
    a2 = fmaf(e, (float)q.z, a2 * f);
    a3 = fmaf(e, (float)q.w, a3 * f);
  }
  float omx = __shfl_xor(mx, 32);
  float osm = __shfl_xor(sm, 32);
  float o0 = __shfl_xor(a0, 32), o1 = __shfl_xor(a1, 32);
  float o2 = __shfl_xor(a2, 32), o3 = __shfl_xor(a3, 32);
  float nm2 = fmaxf(mx, omx);
  float f1 = __expf(mx - nm2), f2 = __expf(omx - nm2);
  sm = sm * f1 + osm * f2;
  a0 = a0 * f1 + o0 * f2;
  a1 = a1 * f1 + o1 * f2;
  a2 = a2 * f1 + o2 * f2;
  a3 = a3 * f1 + o3 * f2;
  float inv = sm > 0.f ? 1.f / sm : 0.f;
  if (half_ == 0) {
    const float4 bv = *(const float4*)(bias + m * NF + c0);
    float q0 = fmaf(a0, inv, bv.x);
    float q1 = fmaf(a1, inv, bv.y);
    float q2 = fmaf(a2, inv, bv.z);
    float q3 = fmaf(a3, inv, bv.w);
    q0 = q0 > 0.f ? q0 : __expf(q0) - 1.f;
    q1 = q1 > 0.f ? q1 : __expf(q1) - 1.f;
    q2 = q2 > 0.f ? q2 : __expf(q2) - 1.f;
    q3 = q3 > 0.f ? q3 : __expf(q3) - 1.f;
    *(float4*)(aggr + (size_t)wid * NF + c0) = make_float4(q0, q1, q2, q3);
    half4 zo = {(_Float16)q0, (_Float16)q1, (_Float16)q2, (_Float16)q3};
    *(half4*)(zh + (size_t)wid * NF + c0) = zo;
  }
}

// ---- semantic: wsum[m] = sum_n w2 . tanh(zh[n,m,:] @ W1 + b1), MFMA ----
// grid 938 blocks x 256; 4 waves x 16 rows; all 128 cols per wave (8 frags)
__global__ __launch_bounds__(256) void k_semgemm_mfma(
    const _Float16* __restrict__ zh, const _Float16* __restrict__ W1T,
    const float* __restrict__ b1, const float* __restrict__ w2,
    float* __restrict__ wsum) {
  __shared__ float msum[NM];
  int tid = threadIdx.x;
  if (tid < NM) msum[tid] = 0.f;
  __syncthreads();
  int wave = tid >> 6, lane = tid & 63;
  int l15 = lane & 15, kslot = lane >> 4;
  int rowbase = blockIdx.x * 64 + wave * 16;
  int arow = rowbase + l15;
  bool aok = arow < NSEG;
  const _Float16* Ap = zh + (size_t)(aok ? arow : 0) * NF + kslot * 8;
  const _Float16* Bp = W1T + (size_t)l15 * HID + kslot * 8;
  f32x4 acc[8];
#pragma unroll
  for (int c = 0; c < 8; ++c) acc[c] = (f32x4){0.f, 0.f, 0.f, 0.f};
#pragma unroll
  for (int kk = 0; kk < 4; ++kk) {
    int k0 = kk * 32;
    half8 a = {};
    if (aok) a = *(const half8*)(Ap + k0);
#pragma unroll
    for (int c = 0; c < 8; ++c) {
      half8 b = *(const half8*)(Bp + (size_t)c * 16 * HID + k0);
      acc[c] = __builtin_amdgcn_mfma_f32_16x16x32_f16(a, b, acc[c], 0, 0, 0);
    }
  }
  float p[4] = {0.f, 0.f, 0.f, 0.f};
#pragma unroll
  for (int c = 0; c < 8; ++c) {
    int col = c * 16 + l15;
    float b1r = b1[col];
    float w2r = w2[col];
#pragma unroll
    for (int j = 0; j < 4; ++j) p[j] += w2r * tanhf(acc[c][j] + b1r);
  }
#pragma unroll
  for (int j = 0; j < 4; ++j) {
#pragma unroll
    for (int off = 1; off < 16; off <<= 1) p[j] += __shfl_xor(p[j], off);
  }
  if (l15 == 0) {
#pragma unroll
    for (int j = 0; j < 4; ++j) {
      int r = rowbase + kslot * 4 + j;
      if (r < NSEG) atomicAdd(&msum[r / NN], p[j]);
    }
  }
  __syncthreads();
  if (tid < NM) {
    float v = msum[tid];
    if (v != 0.f) atomAddF(wsum + tid, v);
  }
}

__global__ void k_beta(const float* __restrict__ wsum, float* __restrict__ beta) {
  if (threadIdx.x == 0 && blockIdx.x == 0) {
    float w0 = wsum[0] / (float)NN;
    float w1 = wsum[1] / (float)NN;
    float w2v = wsum[2] / (float)NN;
    float mx = fmaxf(w0, fmaxf(w1, w2v));
    float e0 = expf(w0 - mx), e1 = expf(w1 - mx), e2 = expf(w2v - mx);
    float s = e0 + e1 + e2;
    beta[0] = e0 / s; beta[1] = e1 / s; beta[2] = e2 / s;
  }
}

__global__ void k_out(const float* __restrict__ z, const float* __restrict__ beta,
                      float* __restrict__ out) {
  int idx = blockIdx.x * 256 + threadIdx.x;
  if (idx >= NN * NF) return;
  out[idx] = beta[0] * z[idx] + beta[1] * z[NN * NF + idx] + beta[2] * z[2 * NN * NF + idx];
}

extern "C" void kernel_launch(void* const* d_in, const int* in_sizes, int n_in,
                              void* d_out, int out_size, void* d_ws, size_t ws_size,
                              hipStream_t stream) {
  (void)in_sizes; (void)n_in; (void)out_size; (void)ws_size;
  const float* h    = (const float*)d_in[0];
  const float* fcW  = (const float*)d_in[1];
  const float* al   = (const float*)d_in[2];
  const float* ar   = (const float*)d_in[3];
  const float* bias = (const float*)d_in[4];
  const float* ew   = (const float*)d_in[5];
  const float* W1   = (const float*)d_in[6];
  const float* b1   = (const float*)d_in[7];
  const float* w2   = (const float*)d_in[8];
  const int* src    = (const int*)d_in[9];
  const int* dst    = (const int*)d_in[10];
  float* out = (float*)d_out;

  float* ws = (float*)d_ws;
  float* aggr  = ws;                          // 7,680,000 f
  float* el    = aggr + (size_t)NM * NN * NF; // 480,000 f
  float* er    = el + NM * NN * NH;           // 480,000 f
  int* deg     = (int*)(er + NM * NN * NH);   // 60,000 i (becomes cursor)
  int* offs    = deg + NSEG;                  // 60,001 i
  int* bsum    = offs + NSEG + 1;             // 256 i
  int* eidx    = bsum + 256;                  // 1,920,000 i
  float* wsum  = (float*)(eidx + NM * NE);    // 8 f
  float* beta  = wsum + 8;                    // 8 f
  size_t w = (size_t)(beta + 8 - ws);
  w = (w + 7) & ~(size_t)7;                   // 32B align
  _Float16* fth = (_Float16*)(ws + w);        // 7,680,000 halfs
  _Float16* h16 = fth + (size_t)NM * NN * NF; // 5,120,000 halfs
  _Float16* WT  = h16 + (size_t)NN * NIN;     // 98,304 halfs
  _Float16* W1T = WT + NM * NIN * NF;         // 16,384 halfs
  _Float16* zh  = W1T + NF * HID;             // 7,680,000 halfs
  // total ~84 MB (< ws_size proven >=89 MB by round-4 fp16 path activation)

  hipLaunchKernelGGL(k_prep, dim3(5000), dim3(256), 0, stream,
                     h, fcW, W1, h16, WT, W1T, deg, wsum);
  hipLaunchKernelGGL(k_count, dim3(7500), dim3(256), 0, stream, dst, deg);
  hipLaunchKernelGGL(k_scan1, dim3(SCAN_BLKS), dim3(256), 0, stream, deg, offs, bsum);
  hipLaunchKernelGGL(k_scan2, dim3(1), dim3(256), 0, stream, bsum, offs);
  hipLaunchKernelGGL(k_scan3, dim3(SCAN_BLKS), dim3(256), 0, stream, offs, bsum, deg);
  hipLaunchKernelGGL(k_fill, dim3(7500), dim3(256), 0, stream, dst, deg, eidx);
  hipLaunchKernelGGL(k_gemm_mfma, dim3(313, 6), dim3(256), 0, stream, h16, WT, fth);
  hipLaunchKernelGGL(k_elr, dim3(1875), dim3(256), 0, stream, fth, al, ar, el, er);
  hipLaunchKernelGGL(k_aggr2, dim3(15000), dim3(256), 0, stream,
                     offs, eidx, src, ew, el, er, fth, bias, aggr, zh);
  hipLaunchKernelGGL(k_semgemm_mfma, dim3(938), dim3(256), 0, stream,
                     zh, W1T, b1, w2, wsum);
  hipLaunchKernelGGL(k_beta, dim3(1), dim3(64), 0, stream, wsum, beta);
  hipLaunchKernelGGL(k_out, dim3(10000), dim3(256), 0, stream, aggr, beta, out);
}

// Round 6
// 509.486 us; speedup vs baseline: 12.2851x; 1.0079x over previous
//
#include <hip/hip_runtime.h>
#include <math.h>

#define NN 20000
#define NE 640000
#define NIN 256
#define NH 8
#define HD 16
#define NM 3
#define NF 128   // H*D
#define HID 128
#define NSEG (NM * NN)
#define SCH ((NSEG + 1023) / 1024)   // elems per thread in single-block scan

typedef __attribute__((ext_vector_type(4))) _Float16 half4;
typedef __attribute__((ext_vector_type(8))) _Float16 half8;
typedef __attribute__((ext_vector_type(4))) float f32x4;

__device__ __forceinline__ void atomAddF(float* p, float v) {
  unsafeAtomicAdd(p, v);   // native global_atomic_add_f32 on gfx950
}

// ---- prep: fp16 conversions + degree count (deg pre-zeroed by memset) ----
__global__ void k_prep(const float* __restrict__ h, const float* __restrict__ fcW,
                       const float* __restrict__ W1, const int* __restrict__ dst,
                       _Float16* __restrict__ h16, _Float16* __restrict__ WT,
                       _Float16* __restrict__ W1T, int* __restrict__ deg) {
  int t = blockIdx.x * 256 + threadIdx.x;
  if (t < NN * NIN / 4) {
    float4 v = *(const float4*)(h + 4 * t);
    half4 o = {(_Float16)v.x, (_Float16)v.y, (_Float16)v.z, (_Float16)v.w};
    *(half4*)(h16 + 4 * t) = o;
  }
  if (t < NM * NIN * NF) {              // WT[(m*128+n)*256+k] = fcW[m][k][n]
    int mm = t >> 15;
    int n = (t >> 8) & 127;
    int k = t & 255;
    WT[t] = (_Float16)fcW[(mm << 15) + (k << 7) + n];
  }
  if (t < NF * HID) {                   // W1T[n*128+k] = W1[k][n]
    int n = t >> 7;
    int k = t & 127;
    W1T[t] = (_Float16)W1[k * HID + n];
  }
  if (t < NM * NE) {
    int m = t / NE;
    atomicAdd(deg + m * NN + dst[t], 1);
  }
}

// ---- single-block exclusive scan over deg -> offs (+cursor copy) ----
__global__ __launch_bounds__(1024) void k_scan(const int* __restrict__ deg,
                                               int* __restrict__ offs,
                                               int* __restrict__ cursor) {
  __shared__ int sm[1024];
  int t = threadIdx.x;
  int lo = t * SCH;
  int hi = lo + SCH;
  if (lo > NSEG) lo = NSEG;
  if (hi > NSEG) hi = NSEG;
  int s = 0;
  for (int i = lo; i < hi; ++i) s += deg[i];
  sm[t] = s;
  __syncthreads();
  for (int o = 1; o < 1024; o <<= 1) {
    int x = (t >= o) ? sm[t - o] : 0;
    __syncthreads();
    sm[t] += x;
    __syncthreads();
  }
  int base = sm[t] - s;   // exclusive prefix of this chunk
  for (int i = lo; i < hi; ++i) {
    offs[i] = base;
    cursor[i] = base;
    base += deg[i];
  }
  if (t == 1023) offs[NSEG] = base;
}

// ---- CSR fill with packed edge records {src, ew} ----
__global__ void k_fill(const int* __restrict__ src, const int* __restrict__ dst,
                       const float* __restrict__ ew, int* __restrict__ cursor,
                       int2* __restrict__ erec) {
  int idx = blockIdx.x * 256 + threadIdx.x;
  if (idx >= NM * NE) return;
  int m = idx / NE;
  int pos = atomicAdd(cursor + m * NN + dst[idx], 1);
  erec[pos] = make_int2(src[idx], __float_as_int(ew[idx]));
}

// ---- ft(fp16) = h16 @ WT via mfma_f32_16x16x32_f16, fused el/er epilogue ----
// grid (ceil(NN/64), 6): y -> (m = y>>1, cin = (y&1)*64). 4 waves, 16 rows each.
__global__ __launch_bounds__(256) void k_gemm_elr(const _Float16* __restrict__ h16,
                                                  const _Float16* __restrict__ WT,
                                                  const float* __restrict__ al,
                                                  const float* __restrict__ ar,
                                                  _Float16* __restrict__ fth,
                                                  float* __restrict__ el,
                                                  float* __restrict__ er) {
  int tid = threadIdx.x;
  int wave = tid >> 6, lane = tid & 63;
  int l15 = lane & 15, kslot = lane >> 4;
  int m = blockIdx.y >> 1;
  int cin = (blockIdx.y & 1) << 6;
  int rowbase = blockIdx.x * 64 + wave * 16;
  int arow = rowbase + l15;
  bool aok = arow < NN;
  const _Float16* Ap = h16 + (size_t)(aok ? arow : 0) * NIN + kslot * 8;
  const _Float16* Bp = WT + ((size_t)m * NF + cin + l15) * NIN + kslot * 8;
  f32x4 acc[4];
#pragma unroll
  for (int c = 0; c < 4; ++c) acc[c] = (f32x4){0.f, 0.f, 0.f, 0.f};
#pragma unroll
  for (int kk = 0; kk < 8; ++kk) {
    int k0 = kk * 32;
    half8 a = {};
    if (aok) a = *(const half8*)(Ap + k0);
#pragma unroll
    for (int c = 0; c < 4; ++c) {
      half8 b = *(const half8*)(Bp + (size_t)c * 16 * NIN + k0);
      acc[c] = __builtin_amdgcn_mfma_f32_16x16x32_f16(a, b, acc[c], 0, 0, 0);
    }
  }
  // fth stores
  int orow0 = rowbase + kslot * 4;
#pragma unroll
  for (int j = 0; j < 4; ++j) {
    int r = orow0 + j;
    if (r < NN) {
      _Float16* op = fth + ((size_t)m * NN + r) * NF + cin + l15;
#pragma unroll
      for (int c = 0; c < 4; ++c) op[c * 16] = (_Float16)acc[c][j];
    }
  }
  // fused el/er: head for col-group c is cin/16 + c; d index = l15
  float alr[4], arr_[4];
#pragma unroll
  for (int c = 0; c < 4; ++c) {
    int head = (cin >> 4) + c;
    alr[c] = al[(m * NH + head) * HD + l15];
    arr_[c] = ar[(m * NH + head) * HD + l15];
  }
#pragma unroll
  for (int c = 0; c < 4; ++c) {
    int head = (cin >> 4) + c;
#pragma unroll
    for (int j = 0; j < 4; ++j) {
      float v = acc[c][j] * alr[c];
      float u = acc[c][j] * arr_[c];
#pragma unroll
      for (int off = 1; off < 16; off <<= 1) {
        v += __shfl_xor(v, off);
        u += __shfl_xor(u, off);
      }
      int r = orow0 + j;
      if (l15 == 0 && r < NN) {
        size_t idx = ((size_t)m * NN + r) * NH + head;
        el[idx] = v;
        er[idx] = u;
      }
    }
  }
}

// ---- fused per-dst ONLINE softmax + aggregation ----
// one wave per (m, dst); 4 edges/iter (16 lanes/edge, 8 cols/lane, fp16 gather)
__global__ __launch_bounds__(256) void k_aggr4(
    const int* __restrict__ offs, const int2* __restrict__ erec,
    const float* __restrict__ el, const float* __restrict__ er,
    const _Float16* __restrict__ fth, const float* __restrict__ bias,
    _Float16* __restrict__ zh) {
  int wid = (blockIdx.x * 256 + threadIdx.x) >> 6;
  int lane = threadIdx.x & 63;
  if (wid >= NSEG) return;
  int m = wid / NN;
  int beg = offs[wid], end = offs[wid + 1];
  int g = lane >> 4, l16 = lane & 15;
  int h2 = l16 >> 1;
  int c0 = l16 * 8;
  float er2 = er[wid * NH + h2];
  const float* elm = el + (size_t)m * NN * NH;
  const _Float16* fhm = fth + (size_t)m * NN * NF;

  float mx = -1e30f, sm = 0.f;
  float acc[8] = {};
#pragma unroll 2
  for (int i = beg + g; i < end; i += 4) {
    int2 e2 = erec[i];
    int s = e2.x;
    float w = __int_as_float(e2.y);
    float x = (elm[s * NH + h2] + er2) * w;
    x = x > 0.f ? x : 0.2f * x;
    float nmx = fmaxf(mx, x);
    float f = __expf(mx - nmx);
    float e = __expf(x - nmx);
    mx = nmx;
    sm = sm * f + e;
    half8 q = *(const half8*)(fhm + (size_t)s * NF + c0);
#pragma unroll
    for (int k2 = 0; k2 < 8; ++k2)
      acc[k2] = fmaf(e, (float)q[k2], acc[k2] * f);
  }
  // merge the 4 edge-groups (lanes l, l^16, l^32, l^48 share columns)
#pragma unroll
  for (int d = 16; d <= 32; d <<= 1) {
    float omx = __shfl_xor(mx, d);
    float osm = __shfl_xor(sm, d);
    float nmx = fmaxf(mx, omx);
    float f1 = __expf(mx - nmx), f2 = __expf(omx - nmx);
    sm = sm * f1 + osm * f2;
#pragma unroll
    for (int k2 = 0; k2 < 8; ++k2) {
      float o = __shfl_xor(acc[k2], d);
      acc[k2] = acc[k2] * f1 + o * f2;
    }
    mx = nmx;
  }
  if (g == 0) {
    float inv = sm > 0.f ? 1.f / sm : 0.f;
    const float4 b0 = *(const float4*)(bias + m * NF + c0);
    const float4 b1 = *(const float4*)(bias + m * NF + c0 + 4);
    float bv[8] = {b0.x, b0.y, b0.z, b0.w, b1.x, b1.y, b1.z, b1.w};
    half8 zo;
#pragma unroll
    for (int k2 = 0; k2 < 8; ++k2) {
      float q = fmaf(acc[k2], inv, bv[k2]);
      q = q > 0.f ? q : __expf(q) - 1.f;
      zo[k2] = (_Float16)q;
    }
    *(half8*)(zh + (size_t)wid * NF + c0) = zo;
  }
}

// ---- semantic: wsum[m] = sum_n w2 . tanh(zh[n,m,:] @ W1 + b1), MFMA ----
__global__ __launch_bounds__(256) void k_semgemm_mfma(
    const _Float16* __restrict__ zh, const _Float16* __restrict__ W1T,
    const float* __restrict__ b1, const float* __restrict__ w2,
    float* __restrict__ wsum) {
  __shared__ float msum[NM];
  int tid = threadIdx.x;
  if (tid < NM) msum[tid] = 0.f;
  __syncthreads();
  int wave = tid >> 6, lane = tid & 63;
  int l15 = lane & 15, kslot = lane >> 4;
  int rowbase = blockIdx.x * 64 + wave * 16;
  int arow = rowbase + l15;
  bool aok = arow < NSEG;
  const _Float16* Ap = zh + (size_t)(aok ? arow : 0) * NF + kslot * 8;
  const _Float16* Bp = W1T + (size_t)l15 * HID + kslot * 8;
  f32x4 acc[8];
#pragma unroll
  for (int c = 0; c < 8; ++c) acc[c] = (f32x4){0.f, 0.f, 0.f, 0.f};
#pragma unroll
  for (int kk = 0; kk < 4; ++kk) {
    int k0 = kk * 32;
    half8 a = {};
    if (aok) a = *(const half8*)(Ap + k0);
#pragma unroll
    for (int c = 0; c < 8; ++c) {
      half8 b = *(const half8*)(Bp + (size_t)c * 16 * HID + k0);
      acc[c] = __builtin_amdgcn_mfma_f32_16x16x32_f16(a, b, acc[c], 0, 0, 0);
    }
  }
  float p[4] = {0.f, 0.f, 0.f, 0.f};
#pragma unroll
  for (int c = 0; c < 8; ++c) {
    int col = c * 16 + l15;
    float b1r = b1[col];
    float w2r = w2[col];
#pragma unroll
    for (int j = 0; j < 4; ++j) p[j] += w2r * tanhf(acc[c][j] + b1r);
  }
#pragma unroll
  for (int j = 0; j < 4; ++j) {
#pragma unroll
    for (int off = 1; off < 16; off <<= 1) p[j] += __shfl_xor(p[j], off);
  }
  if (l15 == 0) {
#pragma unroll
    for (int j = 0; j < 4; ++j) {
      int r = rowbase + kslot * 4 + j;
      if (r < NSEG) atomicAdd(&msum[r / NN], p[j]);
    }
  }
  __syncthreads();
  if (tid < NM) {
    float v = msum[tid];
    if (v != 0.f) atomAddF(wsum + tid, v);
  }
}

// ---- output combine, beta computed inline from wsum ----
__global__ void k_out(const _Float16* __restrict__ zh, const float* __restrict__ wsum,
                      float* __restrict__ out) {
  int idx = blockIdx.x * 256 + threadIdx.x;
  if (idx >= NN * NF) return;
  float w0 = wsum[0] * (1.f / NN);
  float w1 = wsum[1] * (1.f / NN);
  float w2v = wsum[2] * (1.f / NN);
  float mx = fmaxf(w0, fmaxf(w1, w2v));
  float e0 = __expf(w0 - mx), e1 = __expf(w1 - mx), e2 = __expf(w2v - mx);
  float inv = 1.f / (e0 + e1 + e2);
  float z0 = (float)zh[idx];
  float z1 = (float)zh[(size_t)NN * NF + idx];
  float z2 = (float)zh[(size_t)2 * NN * NF + idx];
  out[idx] = (e0 * z0 + e1 * z1 + e2 * z2) * inv;
}

extern "C" void kernel_launch(void* const* d_in, const int* in_sizes, int n_in,
                              void* d_out, int out_size, void* d_ws, size_t ws_size,
                              hipStream_t stream) {
  (void)in_sizes; (void)n_in; (void)out_size; (void)ws_size;
  const float* h    = (const float*)d_in[0];
  const float* fcW  = (const float*)d_in[1];
  const float* al   = (const float*)d_in[2];
  const float* ar   = (const float*)d_in[3];
  const float* bias = (const float*)d_in[4];
  const float* ew   = (const float*)d_in[5];
  const float* W1   = (const float*)d_in[6];
  const float* b1   = (const float*)d_in[7];
  const float* w2   = (const float*)d_in[8];
  const int* src    = (const int*)d_in[9];
  const int* dst    = (const int*)d_in[10];
  float* out = (float*)d_out;

  char* base = (char*)d_ws;
  size_t o = 0;
  int* deg    = (int*)(base + o); o += (size_t)NSEG * 4;
  float* wsum = (float*)(base + o); o += 8 * 4;          // memset covers deg+wsum
  size_t zero_bytes = o;
  int* offs   = (int*)(base + o); o += (size_t)(NSEG + 1) * 4;
  int* cursor = (int*)(base + o); o += (size_t)NSEG * 4;
  o = (o + 7) & ~(size_t)7;
  int2* erec  = (int2*)(base + o); o += (size_t)NM * NE * 8;
  float* el   = (float*)(base + o); o += (size_t)NSEG * NH * 4;
  float* er   = (float*)(base + o); o += (size_t)NSEG * NH * 4;
  _Float16* fth = (_Float16*)(base + o); o += (size_t)NM * NN * NF * 2;
  _Float16* h16 = (_Float16*)(base + o); o += (size_t)NN * NIN * 2;
  _Float16* WT  = (_Float16*)(base + o); o += (size_t)NM * NIN * NF * 2;
  _Float16* W1T = (_Float16*)(base + o); o += (size_t)NF * HID * 2;
  _Float16* zh  = (_Float16*)(base + o); o += (size_t)NM * NN * NF * 2;
  // total ~61 MB

  hipMemsetAsync(deg, 0, zero_bytes, stream);
  hipLaunchKernelGGL(k_prep, dim3(7500), dim3(256), 0, stream,
                     h, fcW, W1, dst, h16, WT, W1T, deg);
  hipLaunchKernelGGL(k_scan, dim3(1), dim3(1024), 0, stream, deg, offs, cursor);
  hipLaunchKernelGGL(k_fill, dim3(7500), dim3(256), 0, stream, src, dst, ew, cursor, erec);
  hipLaunchKernelGGL(k_gemm_elr, dim3(313, 6), dim3(256), 0, stream,
                     h16, WT, al, ar, fth, el, er);
  hipLaunchKernelGGL(k_aggr4, dim3(15000), dim3(256), 0, stream,
                     offs, erec, el, er, fth, bias, zh);
  hipLaunchKernelGGL(k_semgemm_mfma, dim3(938), dim3(256), 0, stream,
                     zh, W1T, b1, w2, wsum);
  hipLaunchKernelGGL(k_out, dim3(10000), dim3(256), 0, stream, zh, wsum, out);
}